// Round 1
// baseline (731.255 us; speedup 1.0000x reference)
//
#include <hip/hip_runtime.h>
#include <hip/hip_bf16.h>
#include <math.h>

#define B 4
#define T 4096
#define DEMB 512
#define DH 64

// ---------------------------------------------------------------------------
// QKV projection: for each row of x [B*T, 512], compute Q,K,V rows [64] each.
// 8 rows per block; x rows staged in LDS (all reads are LDS broadcasts);
// 192 active threads each own one (matrix m, output h) pair and stream the
// 512-long weight row via float4 (lines stay L1-resident across c-iters).
// ---------------------------------------------------------------------------
__global__ __launch_bounds__(256) void qkv_proj_kernel(
    const float* __restrict__ x,
    const float* __restrict__ Wq, const float* __restrict__ bq,
    const float* __restrict__ Wk, const float* __restrict__ bk,
    const float* __restrict__ Wv, const float* __restrict__ bv,
    float* __restrict__ Q, float* __restrict__ K, float* __restrict__ V)
{
    __shared__ float xs[8 * DEMB];
    const int tid = threadIdx.x;
    const size_t row0 = (size_t)blockIdx.x * 8;
    const float* xrow = x + row0 * DEMB;
    for (int i = tid; i < 8 * DEMB; i += 256) xs[i] = xrow[i];
    __syncthreads();

    if (tid < 192) {
        const int m = tid >> 6;      // 0=Q, 1=K, 2=V
        const int h = tid & 63;
        const float* W = (m == 0 ? Wq : (m == 1 ? Wk : Wv)) + (size_t)h * DEMB;
        const float bias = (m == 0 ? bq : (m == 1 ? bk : bv))[h];
        float acc[8];
#pragma unroll
        for (int r = 0; r < 8; ++r) acc[r] = bias;
        const float4* W4 = (const float4*)W;
#pragma unroll 4
        for (int c4 = 0; c4 < DEMB / 4; ++c4) {
            const float4 w = W4[c4];
            const int c = c4 * 4;
#pragma unroll
            for (int r = 0; r < 8; ++r) {
                acc[r] += w.x * xs[r * DEMB + c]
                        + w.y * xs[r * DEMB + c + 1]
                        + w.z * xs[r * DEMB + c + 2]
                        + w.w * xs[r * DEMB + c + 3];
            }
        }
        float* out = (m == 0 ? Q : (m == 1 ? K : V));
#pragma unroll
        for (int r = 0; r < 8; ++r) out[(row0 + r) * DH + h] = acc[r];
    }
}

// ---------------------------------------------------------------------------
// Causal attention, flash-style online softmax.
// One block = 4 query rows (q0..q0+3) of one batch. 256 threads.
// K-loop over chunks of 256 columns, only chunks with k0 <= q0 (causality;
// q0 % 4 == 0 and k0 % 256 == 0 make the loop bound exact).
// Phase A: thread t scores column k0+t against all 4 q rows -> sc[r][t].
// Phase B: wave r reduces max/sum for row r (shuffles), writes alphas back.
// Phase C: thread (h = t&63, j = t>>6) accumulates O[r][h] partials over
//          kk = j, j+4, ... with coalesced V reads and LDS-broadcast alphas.
// Epilogue: reduce the 4 j-partials via LDS, divide by l, multiply sqrt(64)=8.
// ---------------------------------------------------------------------------
__global__ __launch_bounds__(256) void attn_kernel(
    const float* __restrict__ Q, const float* __restrict__ K,
    const float* __restrict__ V, float* __restrict__ O)
{
    const int tid  = threadIdx.x;
    const int lane = tid & 63;
    const int wv   = tid >> 6;      // 0..3
    const int b    = blockIdx.x / (T / 4);
    const int q0   = (blockIdx.x % (T / 4)) * 4;

    __shared__ float qs[4][DH];
    __shared__ float sc[4][256];
    __shared__ float mrow[4], lrow[4], srow[4];
    __shared__ float accs[4][4][DH];   // [j][r][h]

    const size_t base = (size_t)b * T;

    if (tid < 4 * DH) {
        const int r = tid >> 6, h = tid & 63;
        qs[r][h] = Q[(base + q0 + r) * DH + h];
    }
    if (tid < 4) { mrow[tid] = -INFINITY; lrow[tid] = 0.f; }
    __syncthreads();

    const int h = tid & 63;
    const int j = tid >> 6;
    float oacc[4] = {0.f, 0.f, 0.f, 0.f};

    for (int k0 = 0; k0 <= q0; k0 += 256) {
        // ---- Phase A: raw scores for 4 rows, this thread's k column
        {
            const int k = k0 + tid;
            const float4* K4 = (const float4*)(K + (base + k) * DH);
            float s0 = 0.f, s1 = 0.f, s2 = 0.f, s3 = 0.f;
#pragma unroll
            for (int c4 = 0; c4 < DH / 4; ++c4) {
                const float4 kv = K4[c4];
                const int c = c4 * 4;
                s0 += kv.x * qs[0][c] + kv.y * qs[0][c + 1] + kv.z * qs[0][c + 2] + kv.w * qs[0][c + 3];
                s1 += kv.x * qs[1][c] + kv.y * qs[1][c + 1] + kv.z * qs[1][c + 2] + kv.w * qs[1][c + 3];
                s2 += kv.x * qs[2][c] + kv.y * qs[2][c + 1] + kv.z * qs[2][c + 2] + kv.w * qs[2][c + 3];
                s3 += kv.x * qs[3][c] + kv.y * qs[3][c + 1] + kv.z * qs[3][c + 2] + kv.w * qs[3][c + 3];
            }
            sc[0][tid] = (k <= q0 + 0) ? s0 : -INFINITY;
            sc[1][tid] = (k <= q0 + 1) ? s1 : -INFINITY;
            sc[2][tid] = (k <= q0 + 2) ? s2 : -INFINITY;
            sc[3][tid] = (k <= q0 + 3) ? s3 : -INFINITY;
        }
        __syncthreads();

        // ---- Phase B: online softmax update; wave wv owns row wv
        {
            float v0 = sc[wv][lane      ];
            float v1 = sc[wv][lane +  64];
            float v2 = sc[wv][lane + 128];
            float v3 = sc[wv][lane + 192];
            float mx = fmaxf(fmaxf(v0, v1), fmaxf(v2, v3));
#pragma unroll
            for (int off = 32; off > 0; off >>= 1)
                mx = fmaxf(mx, __shfl_down(mx, off, 64));
            mx = __shfl(mx, 0, 64);
            const float mold = mrow[wv];
            const float newm = fmaxf(mold, mx);   // finite: every chunk has >=1 valid col
            const float a0 = expf(v0 - newm);     // expf(-inf)=0 handles the mask
            const float a1 = expf(v1 - newm);
            const float a2 = expf(v2 - newm);
            const float a3 = expf(v3 - newm);
            float sum = a0 + a1 + a2 + a3;
#pragma unroll
            for (int off = 32; off > 0; off >>= 1)
                sum += __shfl_down(sum, off, 64);
            sc[wv][lane      ] = a0;
            sc[wv][lane +  64] = a1;
            sc[wv][lane + 128] = a2;
            sc[wv][lane + 192] = a3;
            if (lane == 0) {
                const float scale = expf(mold - newm);  // first chunk: exp(-inf)=0
                mrow[wv] = newm;
                lrow[wv] = lrow[wv] * scale + sum;
                srow[wv] = scale;
            }
        }
        __syncthreads();

        // ---- Phase C: accumulate O partials
        {
            const float s0 = srow[0], s1 = srow[1], s2 = srow[2], s3 = srow[3];
            oacc[0] *= s0; oacc[1] *= s1; oacc[2] *= s2; oacc[3] *= s3;
            const float* Vb = V + (base + k0) * DH + h;
            for (int kk = j; kk < 256; kk += 4) {
                const float v = Vb[(size_t)kk * DH];
                oacc[0] += sc[0][kk] * v;
                oacc[1] += sc[1][kk] * v;
                oacc[2] += sc[2][kk] * v;
                oacc[3] += sc[3][kk] * v;
            }
        }
        __syncthreads();   // sc is overwritten by next Phase A
    }

    // ---- Epilogue: reduce j-partials, normalize, scale by sqrt(d_h)=8
#pragma unroll
    for (int r = 0; r < 4; ++r) accs[j][r][h] = oacc[r];
    __syncthreads();
    if (tid < DH) {
#pragma unroll
        for (int r = 0; r < 4; ++r) {
            const float s = accs[0][r][tid] + accs[1][r][tid]
                          + accs[2][r][tid] + accs[3][r][tid];
            O[(base + q0 + r) * DH + tid] = s / lrow[r] * 8.0f;
        }
    }
}

extern "C" void kernel_launch(void* const* d_in, const int* in_sizes, int n_in,
                              void* d_out, int out_size, void* d_ws, size_t ws_size,
                              hipStream_t stream) {
    const float* x  = (const float*)d_in[0];
    const float* Wq = (const float*)d_in[1];
    const float* bq = (const float*)d_in[2];
    const float* Wk = (const float*)d_in[3];
    const float* bk = (const float*)d_in[4];
    const float* Wv = (const float*)d_in[5];
    const float* bv = (const float*)d_in[6];
    float* out = (float*)d_out;

    float* Q = (float*)d_ws;                    // [B*T, 64]
    float* K = Q + (size_t)B * T * DH;          // [B*T, 64]
    float* V = K + (size_t)B * T * DH;          // [B*T, 64]  (12 MB total fp32)

    qkv_proj_kernel<<<dim3(B * T / 8), dim3(256), 0, stream>>>(
        x, Wq, bq, Wk, bk, Wv, bv, Q, K, V);
    attn_kernel<<<dim3(B * (T / 4)), dim3(256), 0, stream>>>(Q, K, V, out);
}

// Round 3
// 448.357 us; speedup vs baseline: 1.6310x; 1.6310x over previous
//
#include <hip/hip_runtime.h>
#include <hip/hip_bf16.h>
#include <math.h>

#define B 4
#define T 4096
#define DEMB 512
#define DH 64

typedef unsigned short u16;
typedef __attribute__((ext_vector_type(4))) float f32x4;
typedef __attribute__((ext_vector_type(8))) short bf16x8;

__device__ __forceinline__ u16 f2bf(float f) {
    union { float f; unsigned u; } v; v.f = f;
    const unsigned r = v.u + 0x7FFFu + ((v.u >> 16) & 1u);   // RNE; inputs finite
    return (u16)(r >> 16);
}
__device__ __forceinline__ float bf2f(u16 h) {
    union { unsigned u; float f; } v; v.u = ((unsigned)h) << 16;
    return v.f;
}

// ---------------------------------------------------------------------------
// QKV projection (fp32 VALU). Emits Q,K as SPLIT bf16 (hi + residual-lo)
// for fp32-emulated QK^T; V as single bf16, transposed: Vt[b][h][t].
// Block = 64 rows of x; lane = row. Wave w owns 48 (m,h) output pairs.
// W float4 loads are wave-uniform broadcasts; x chunk lives in registers.
// ---------------------------------------------------------------------------
__global__ __launch_bounds__(256) void qkv_proj(
    const float* __restrict__ x,
    const float* __restrict__ Wq, const float* __restrict__ bq,
    const float* __restrict__ Wk, const float* __restrict__ bk,
    const float* __restrict__ Wv, const float* __restrict__ bv,
    u16* __restrict__ Qh, u16* __restrict__ Ql,
    u16* __restrict__ Kh, u16* __restrict__ Kl,
    u16* __restrict__ Vt)
{
    const int tid  = threadIdx.x;
    const int wv   = tid >> 6;
    const int lane = tid & 63;
    const size_t grow = (size_t)blockIdx.x * 64 + lane;
    const float* __restrict__ xrow = x + grow * DEMB;

    float acc[48];
#pragma unroll
    for (int j = 0; j < 48; ++j) acc[j] = 0.f;

    for (int cc = 0; cc < DEMB; cc += 32) {
        float4 xc[8];
        const float4* x4p = (const float4*)(xrow + cc);
#pragma unroll
        for (int u = 0; u < 8; ++u) xc[u] = x4p[u];
#pragma unroll
        for (int j = 0; j < 48; ++j) {
            const int p = wv * 48 + j;            // wave-uniform
            const int m = p >> 6, h = p & 63;
            const float4* W4 = (const float4*)((m == 0 ? Wq : (m == 1 ? Wk : Wv))
                                               + (size_t)h * DEMB + cc);
            float s = 0.f;
#pragma unroll
            for (int u = 0; u < 8; ++u) {
                const float4 w = W4[u];
                s += w.x * xc[u].x + w.y * xc[u].y + w.z * xc[u].z + w.w * xc[u].w;
            }
            acc[j] += s;
        }
    }

    const size_t bb   = grow / T;     // uniform per block (64 | T)
    const size_t trow = grow - bb * T;
#pragma unroll
    for (int j = 0; j < 48; ++j) {
        const int p = wv * 48 + j;
        const int m = p >> 6, h = p & 63;
        const float bias = (m == 0 ? bq : (m == 1 ? bk : bv))[h];
        const float v = acc[j] + bias;
        if (m == 2) {
            Vt[(bb * DH + h) * T + trow] = f2bf(v);
        } else {
            const u16 hi = f2bf(v);
            const u16 lo = f2bf(v - bf2f(hi));
            if (m == 0) { Qh[grow * DH + h] = hi; Ql[grow * DH + h] = lo; }
            else        { Kh[grow * DH + h] = hi; Kl[grow * DH + h] = lo; }
        }
    }
}

// ---------------------------------------------------------------------------
// Causal flash attention, bf16 MFMA (16x16x32), split-precision QK^T:
//   S = Qh*Kh + Qh*Kl + Ql*Kh   (fp32-emulated; Ql*Kl dropped)
// Grid = 1024 blocks (batch = bid>>8, swizzled group). Block = 4 waves on
// the same 16-row q-group; k-chunks (64 cols) round-robin by wave; per-wave
// online softmax (m,l,O); flash-combine via LDS at the end.
// P: C/D->A layout via per-wave LDS buffer (same-wave DS is in-order).
// Softmax denominator sums bf16-ROUNDED p so PV numerator rounding cancels.
// ---------------------------------------------------------------------------
__global__ __launch_bounds__(256, 4) void attn_mfma(
    const u16* __restrict__ Qhp, const u16* __restrict__ Qlp,
    const u16* __restrict__ Khp, const u16* __restrict__ Klp,
    const u16* __restrict__ Vt, float* __restrict__ O)
{
    __shared__ u16   Plds[4][16][80];   // pad 64->80 halves: 16B-aligned rows
    __shared__ float Olds[4][16][68];   // pad 64->68
    __shared__ float mlds[4][16], llds[4][16];

    const int tid  = threadIdx.x;
    const int wv   = tid >> 6;
    const int lane = tid & 63;
    const int i16  = lane & 15;
    const int quad = lane >> 4;

    const int bb   = blockIdx.x >> 8;                             // batch
    const int g    = (int)(((blockIdx.x & 255) + bb * 64) & 255); // 16-row group
    const size_t base = (size_t)bb * T;
    const int row0 = g * 16;
    const int nchunks = (g >> 2) + 1;

    const u16* qrowh = Qhp + (base + row0 + i16) * DH;
    const u16* qrowl = Qlp + (base + row0 + i16) * DH;
    const bf16x8 qh0 = *(const bf16x8*)(qrowh + quad * 8);
    const bf16x8 qh1 = *(const bf16x8*)(qrowh + 32 + quad * 8);
    const bf16x8 ql0 = *(const bf16x8*)(qrowl + quad * 8);
    const bf16x8 ql1 = *(const bf16x8*)(qrowl + 32 + quad * 8);

    f32x4 oacc[4];
    float m4[4], l4[4];
    const f32x4 zero = {0.f, 0.f, 0.f, 0.f};
#pragma unroll
    for (int n = 0; n < 4; ++n) oacc[n] = zero;
#pragma unroll
    for (int r = 0; r < 4; ++r) { m4[r] = -INFINITY; l4[r] = 0.f; }

    for (int c = wv; c < nchunks; c += 4) {
        const int kb = c << 6;
        f32x4 s[4];
#pragma unroll
        for (int n = 0; n < 4; ++n) {
            const u16* krh = Khp + (base + kb + n * 16 + i16) * DH;
            const u16* krl = Klp + (base + kb + n * 16 + i16) * DH;
            const bf16x8 kh0 = *(const bf16x8*)(krh + quad * 8);
            const bf16x8 kh1 = *(const bf16x8*)(krh + 32 + quad * 8);
            const bf16x8 kl0 = *(const bf16x8*)(krl + quad * 8);
            const bf16x8 kl1 = *(const bf16x8*)(krl + 32 + quad * 8);
            f32x4 acc = __builtin_amdgcn_mfma_f32_16x16x32_bf16(qh0, kl0, zero, 0, 0, 0);
            acc = __builtin_amdgcn_mfma_f32_16x16x32_bf16(qh1, kl1, acc, 0, 0, 0);
            acc = __builtin_amdgcn_mfma_f32_16x16x32_bf16(ql0, kh0, acc, 0, 0, 0);
            acc = __builtin_amdgcn_mfma_f32_16x16x32_bf16(ql1, kh1, acc, 0, 0, 0);
            acc = __builtin_amdgcn_mfma_f32_16x16x32_bf16(qh0, kh0, acc, 0, 0, 0);
            acc = __builtin_amdgcn_mfma_f32_16x16x32_bf16(qh1, kh1, acc, 0, 0, 0);
            s[n] = acc;
        }
        if (c == nchunks - 1) {     // diagonal chunk: causal mask
#pragma unroll
            for (int n = 0; n < 4; ++n)
#pragma unroll
                for (int r = 0; r < 4; ++r)
                    if (kb + n * 16 + i16 > row0 + quad * 4 + r)
                        s[n][r] = -INFINITY;
        }
        // online softmax; rows quad*4+r, reduce across the 16 lanes of quad
        float alpha[4];
#pragma unroll
        for (int r = 0; r < 4; ++r) {
            float mx = fmaxf(fmaxf(s[0][r], s[1][r]), fmaxf(s[2][r], s[3][r]));
            mx = fmaxf(mx, __shfl_xor(mx, 1, 64));
            mx = fmaxf(mx, __shfl_xor(mx, 2, 64));
            mx = fmaxf(mx, __shfl_xor(mx, 4, 64));
            mx = fmaxf(mx, __shfl_xor(mx, 8, 64));
            const float mnew = fmaxf(m4[r], mx);
            alpha[r] = __expf(m4[r] - mnew);       // first chunk: exp(-inf)=0
            m4[r] = mnew;
#pragma unroll
            for (int n = 0; n < 4; ++n) s[n][r] = __expf(s[n][r] - mnew);
        }
        // P: C/D layout -> LDS (bf16) -> A layout; sum the ROUNDED p for l
        float sum4[4] = {0.f, 0.f, 0.f, 0.f};
#pragma unroll
        for (int n = 0; n < 4; ++n)
#pragma unroll
            for (int r = 0; r < 4; ++r) {
                const u16 pb = f2bf(s[n][r]);
                Plds[wv][quad * 4 + r][n * 16 + i16] = pb;
                sum4[r] += bf2f(pb);
                oacc[n][r] *= alpha[r];
            }
#pragma unroll
        for (int r = 0; r < 4; ++r) {
            float sum = sum4[r];
            sum += __shfl_xor(sum, 1, 64);
            sum += __shfl_xor(sum, 2, 64);
            sum += __shfl_xor(sum, 4, 64);
            sum += __shfl_xor(sum, 8, 64);
            l4[r] = l4[r] * alpha[r] + sum;
        }
        const bf16x8 pf0 = *(const bf16x8*)&Plds[wv][i16][quad * 8];
        const bf16x8 pf1 = *(const bf16x8*)&Plds[wv][i16][32 + quad * 8];
#pragma unroll
        for (int n = 0; n < 4; ++n) {
            const u16* vrow = Vt + ((size_t)bb * DH + n * 16 + i16) * T + kb;
            const bf16x8 vf0 = *(const bf16x8*)(vrow + quad * 8);
            const bf16x8 vf1 = *(const bf16x8*)(vrow + 32 + quad * 8);
            oacc[n] = __builtin_amdgcn_mfma_f32_16x16x32_bf16(pf0, vf0, oacc[n], 0, 0, 0);
            oacc[n] = __builtin_amdgcn_mfma_f32_16x16x32_bf16(pf1, vf1, oacc[n], 0, 0, 0);
        }
    }

    // flash-combine the 4 waves' partial (O, m, l)
#pragma unroll
    for (int r = 0; r < 4; ++r) {
        const int row = quad * 4 + r;
#pragma unroll
        for (int n = 0; n < 4; ++n) Olds[wv][row][n * 16 + i16] = oacc[n][r];
        if (i16 == 0) { mlds[wv][row] = m4[r]; llds[wv][row] = l4[r]; }
    }
    __syncthreads();
    if (wv == 0) {
#pragma unroll
        for (int r = 0; r < 4; ++r) {
            const int row = quad * 4 + r;
            const float mm0 = mlds[0][row], mm1 = mlds[1][row];
            const float mm2 = mlds[2][row], mm3 = mlds[3][row];
            const float ms = fmaxf(fmaxf(mm0, mm1), fmaxf(mm2, mm3));
            const float w0 = __expf(mm0 - ms), w1 = __expf(mm1 - ms);
            const float w2 = __expf(mm2 - ms), w3 = __expf(mm3 - ms);
            const float ll = llds[0][row] * w0 + llds[1][row] * w1
                           + llds[2][row] * w2 + llds[3][row] * w3;
            const float sc = 8.0f / ll;            // post-softmax * sqrt(64)
            float* orow = O + (base + row0 + row) * DH;
#pragma unroll
            for (int n = 0; n < 4; ++n) {
                const int col = n * 16 + i16;
                orow[col] = (Olds[0][row][col] * w0 + Olds[1][row][col] * w1
                           + Olds[2][row][col] * w2 + Olds[3][row][col] * w3) * sc;
            }
        }
    }
}

extern "C" void kernel_launch(void* const* d_in, const int* in_sizes, int n_in,
                              void* d_out, int out_size, void* d_ws, size_t ws_size,
                              hipStream_t stream) {
    const float* x  = (const float*)d_in[0];
    const float* Wq = (const float*)d_in[1];
    const float* bq = (const float*)d_in[2];
    const float* Wk = (const float*)d_in[3];
    const float* bk = (const float*)d_in[4];
    const float* Wv = (const float*)d_in[5];
    const float* bv = (const float*)d_in[6];

    const size_t N = (size_t)B * T * DH;        // 1M elements, 2 MB each bf16
    u16* Qh = (u16*)d_ws;
    u16* Ql = Qh + N;
    u16* Kh = Ql + N;
    u16* Kl = Kh + N;
    u16* Vt = Kl + N;                           // [B, 64, T] transposed

    qkv_proj<<<dim3(B * T / 64), dim3(256), 0, stream>>>(
        x, Wq, bq, Wk, bk, Wv, bv, Qh, Ql, Kh, Kl, Vt);
    attn_mfma<<<dim3(B * (T / 16)), dim3(256), 0, stream>>>(
        Qh, Ql, Kh, Kl, Vt, (float*)d_out);
}

// Round 4
// 246.368 us; speedup vs baseline: 2.9681x; 1.8199x over previous
//
#include <hip/hip_runtime.h>
#include <hip/hip_bf16.h>
#include <math.h>

#define B 4
#define T 4096
#define DEMB 512
#define DH 64

typedef unsigned short u16;
typedef __attribute__((ext_vector_type(4))) float f32x4;
typedef __attribute__((ext_vector_type(8))) short bf16x8;

__device__ __forceinline__ u16 f2bf(float f) {
    union { float f; unsigned u; } v; v.f = f;
    const unsigned r = v.u + 0x7FFFu + ((v.u >> 16) & 1u);   // RNE; inputs finite
    return (u16)(r >> 16);
}
__device__ __forceinline__ float bf2f(u16 h) {
    union { unsigned u; float f; } v; v.u = ((unsigned)h) << 16;
    return v.f;
}

// ---------------------------------------------------------------------------
// W prepass: concat Wq|Wk|Wv -> [192][512], split into hi + residual-lo bf16.
// Row-major [n][k] == B^T fragment layout for mfma_16x16x32.
// ---------------------------------------------------------------------------
__global__ __launch_bounds__(256) void convert_w(
    const float* __restrict__ Wq, const float* __restrict__ Wk,
    const float* __restrict__ Wv, u16* __restrict__ Wh, u16* __restrict__ Wl)
{
    const int idx = blockIdx.x * 256 + threadIdx.x;     // grid covers 192*512
    const int row = idx >> 9;
    const int k   = idx & 511;
    const float* W = row < 64 ? Wq : (row < 128 ? Wk : Wv);
    const float v = W[(row & 63) * DEMB + k];
    const u16 hi = f2bf(v);
    Wh[idx] = hi;
    Wl[idx] = f2bf(v - bf2f(hi));
}

// ---------------------------------------------------------------------------
// QKV projection as split-bf16 MFMA GEMM: [16384x512] x [512x192].
// Grid 512 blocks x 4 waves (2 waves/SIMD). Block = 32 x-rows.
// Stage: x fp32 -> hi/lo bf16 in LDS, k-chunks of 128, row stride 136
//        (2-way bank alias only = free).
// Wave (wv&1) owns 16 rows; (wv>>1) owns 6 of 12 n-tiles (96 cols).
// Per tile: acc += Ah*Bl + Al*Bh + Ah*Bh  (xl*wl ~2^-17, dropped).
// Epilogue: +bias fp32, Q/K -> split bf16 row-major, V -> bf16 transposed.
// ---------------------------------------------------------------------------
__global__ __launch_bounds__(256) void proj_mfma(
    const float* __restrict__ x,
    const u16* __restrict__ Wh, const u16* __restrict__ Wl,
    const float* __restrict__ bq, const float* __restrict__ bk,
    const float* __restrict__ bv,
    u16* __restrict__ Qh, u16* __restrict__ Ql,
    u16* __restrict__ Kh, u16* __restrict__ Kl,
    u16* __restrict__ Vt)
{
    __shared__ u16 xh[32][136], xl[32][136];

    const int tid  = threadIdx.x;
    const int wv   = tid >> 6;
    const int lane = tid & 63;
    const int i16  = lane & 15;
    const int quad = lane >> 4;
    const int mrow0 = (wv & 1) * 16;        // wave's row offset within tile
    const int nh    = wv >> 1;              // n-half: tiles nh*6 .. nh*6+5
    const size_t r0 = (size_t)blockIdx.x * 32;

    f32x4 acc[6];
    const f32x4 zero = {0.f, 0.f, 0.f, 0.f};
#pragma unroll
    for (int n = 0; n < 6; ++n) acc[n] = zero;

    for (int cc = 0; cc < DEMB; cc += 128) {
        __syncthreads();                    // previous chunk's reads done
#pragma unroll
        for (int u = 0; u < 4; ++u) {
            const int idx = tid + 256 * u;  // 0..1023 float4s
            const int row = idx >> 5, c4 = idx & 31;
            const float4 v = *(const float4*)(x + (r0 + row) * DEMB + cc + c4 * 4);
            const u16 h0 = f2bf(v.x), h1 = f2bf(v.y), h2 = f2bf(v.z), h3 = f2bf(v.w);
            ushort4 hv = {h0, h1, h2, h3};
            ushort4 lv = {f2bf(v.x - bf2f(h0)), f2bf(v.y - bf2f(h1)),
                          f2bf(v.z - bf2f(h2)), f2bf(v.w - bf2f(h3))};
            *(ushort4*)&xh[row][c4 * 4] = hv;
            *(ushort4*)&xl[row][c4 * 4] = lv;
        }
        __syncthreads();

#pragma unroll
        for (int kk = 0; kk < 128; kk += 32) {
            const bf16x8 ah = *(const bf16x8*)&xh[mrow0 + i16][kk + quad * 8];
            const bf16x8 al = *(const bf16x8*)&xl[mrow0 + i16][kk + quad * 8];
#pragma unroll
            for (int n = 0; n < 6; ++n) {
                const size_t woff = (size_t)((nh * 6 + n) * 16 + i16) * DEMB
                                  + cc + kk + quad * 8;
                const bf16x8 bh = *(const bf16x8*)(Wh + woff);
                const bf16x8 bl = *(const bf16x8*)(Wl + woff);
                acc[n] = __builtin_amdgcn_mfma_f32_16x16x32_bf16(ah, bl, acc[n], 0, 0, 0);
                acc[n] = __builtin_amdgcn_mfma_f32_16x16x32_bf16(al, bh, acc[n], 0, 0, 0);
                acc[n] = __builtin_amdgcn_mfma_f32_16x16x32_bf16(ah, bh, acc[n], 0, 0, 0);
            }
        }
    }

    const size_t bb = r0 / T;               // batch (uniform; 32 | 4096)
    const size_t t0 = r0 - bb * T;
#pragma unroll
    for (int n = 0; n < 6; ++n) {
        const int col = nh * 96 + n * 16 + i16;     // 0..191
        const int m = col >> 6, h = col & 63;       // m wave-uniform per n
        const float bias = (m == 0 ? bq : (m == 1 ? bk : bv))[h];
#pragma unroll
        for (int r = 0; r < 4; ++r) {
            const int row = mrow0 + quad * 4 + r;   // 0..31
            const float v = acc[n][r] + bias;
            const size_t grow = r0 + row;
            if (m == 2) {
                Vt[(bb * DH + h) * T + t0 + row] = f2bf(v);
            } else {
                const u16 hi = f2bf(v);
                const u16 lo = f2bf(v - bf2f(hi));
                if (m == 0) { Qh[grow * DH + h] = hi; Ql[grow * DH + h] = lo; }
                else        { Kh[grow * DH + h] = hi; Kl[grow * DH + h] = lo; }
            }
        }
    }
}

// ---------------------------------------------------------------------------
// Causal flash attention, bf16 MFMA (16x16x32), split-precision QK^T:
//   S = Qh*Kh + Qh*Kl + Ql*Kh   (fp32-emulated; Ql*Kl dropped)
// Grid = 1024 blocks (batch = bid>>8, swizzled group). Block = 4 waves on
// the same 16-row q-group; k-chunks (64 cols) round-robin by wave; per-wave
// online softmax (m,l,O); flash-combine via LDS at the end.
// ---------------------------------------------------------------------------
__global__ __launch_bounds__(256, 4) void attn_mfma(
    const u16* __restrict__ Qhp, const u16* __restrict__ Qlp,
    const u16* __restrict__ Khp, const u16* __restrict__ Klp,
    const u16* __restrict__ Vt, float* __restrict__ O)
{
    __shared__ u16   Plds[4][16][80];
    __shared__ float Olds[4][16][68];
    __shared__ float mlds[4][16], llds[4][16];

    const int tid  = threadIdx.x;
    const int wv   = tid >> 6;
    const int lane = tid & 63;
    const int i16  = lane & 15;
    const int quad = lane >> 4;

    const int bb   = blockIdx.x >> 8;
    const int g    = (int)(((blockIdx.x & 255) + bb * 64) & 255);
    const size_t base = (size_t)bb * T;
    const int row0 = g * 16;
    const int nchunks = (g >> 2) + 1;

    const u16* qrowh = Qhp + (base + row0 + i16) * DH;
    const u16* qrowl = Qlp + (base + row0 + i16) * DH;
    const bf16x8 qh0 = *(const bf16x8*)(qrowh + quad * 8);
    const bf16x8 qh1 = *(const bf16x8*)(qrowh + 32 + quad * 8);
    const bf16x8 ql0 = *(const bf16x8*)(qrowl + quad * 8);
    const bf16x8 ql1 = *(const bf16x8*)(qrowl + 32 + quad * 8);

    f32x4 oacc[4];
    float m4[4], l4[4];
    const f32x4 zero = {0.f, 0.f, 0.f, 0.f};
#pragma unroll
    for (int n = 0; n < 4; ++n) oacc[n] = zero;
#pragma unroll
    for (int r = 0; r < 4; ++r) { m4[r] = -INFINITY; l4[r] = 0.f; }

    for (int c = wv; c < nchunks; c += 4) {
        const int kb = c << 6;
        f32x4 s[4];
#pragma unroll
        for (int n = 0; n < 4; ++n) {
            const u16* krh = Khp + (base + kb + n * 16 + i16) * DH;
            const u16* krl = Klp + (base + kb + n * 16 + i16) * DH;
            const bf16x8 kh0 = *(const bf16x8*)(krh + quad * 8);
            const bf16x8 kh1 = *(const bf16x8*)(krh + 32 + quad * 8);
            const bf16x8 kl0 = *(const bf16x8*)(krl + quad * 8);
            const bf16x8 kl1 = *(const bf16x8*)(krl + 32 + quad * 8);
            f32x4 a = __builtin_amdgcn_mfma_f32_16x16x32_bf16(qh0, kl0, zero, 0, 0, 0);
            a = __builtin_amdgcn_mfma_f32_16x16x32_bf16(qh1, kl1, a, 0, 0, 0);
            a = __builtin_amdgcn_mfma_f32_16x16x32_bf16(ql0, kh0, a, 0, 0, 0);
            a = __builtin_amdgcn_mfma_f32_16x16x32_bf16(ql1, kh1, a, 0, 0, 0);
            a = __builtin_amdgcn_mfma_f32_16x16x32_bf16(qh0, kh0, a, 0, 0, 0);
            a = __builtin_amdgcn_mfma_f32_16x16x32_bf16(qh1, kh1, a, 0, 0, 0);
            s[n] = a;
        }
        if (c == nchunks - 1) {
#pragma unroll
            for (int n = 0; n < 4; ++n)
#pragma unroll
                for (int r = 0; r < 4; ++r)
                    if (kb + n * 16 + i16 > row0 + quad * 4 + r)
                        s[n][r] = -INFINITY;
        }
        float alpha[4];
#pragma unroll
        for (int r = 0; r < 4; ++r) {
            float mx = fmaxf(fmaxf(s[0][r], s[1][r]), fmaxf(s[2][r], s[3][r]));
            mx = fmaxf(mx, __shfl_xor(mx, 1, 64));
            mx = fmaxf(mx, __shfl_xor(mx, 2, 64));
            mx = fmaxf(mx, __shfl_xor(mx, 4, 64));
            mx = fmaxf(mx, __shfl_xor(mx, 8, 64));
            const float mnew = fmaxf(m4[r], mx);
            alpha[r] = __expf(m4[r] - mnew);
            m4[r] = mnew;
#pragma unroll
            for (int n = 0; n < 4; ++n) s[n][r] = __expf(s[n][r] - mnew);
        }
        float sum4[4] = {0.f, 0.f, 0.f, 0.f};
#pragma unroll
        for (int n = 0; n < 4; ++n)
#pragma unroll
            for (int r = 0; r < 4; ++r) {
                const u16 pb = f2bf(s[n][r]);
                Plds[wv][quad * 4 + r][n * 16 + i16] = pb;
                sum4[r] += bf2f(pb);
                oacc[n][r] *= alpha[r];
            }
#pragma unroll
        for (int r = 0; r < 4; ++r) {
            float sum = sum4[r];
            sum += __shfl_xor(sum, 1, 64);
            sum += __shfl_xor(sum, 2, 64);
            sum += __shfl_xor(sum, 4, 64);
            sum += __shfl_xor(sum, 8, 64);
            l4[r] = l4[r] * alpha[r] + sum;
        }
        const bf16x8 pf0 = *(const bf16x8*)&Plds[wv][i16][quad * 8];
        const bf16x8 pf1 = *(const bf16x8*)&Plds[wv][i16][32 + quad * 8];
#pragma unroll
        for (int n = 0; n < 4; ++n) {
            const u16* vrow = Vt + ((size_t)bb * DH + n * 16 + i16) * T + kb;
            const bf16x8 vf0 = *(const bf16x8*)(vrow + quad * 8);
            const bf16x8 vf1 = *(const bf16x8*)(vrow + 32 + quad * 8);
            oacc[n] = __builtin_amdgcn_mfma_f32_16x16x32_bf16(pf0, vf0, oacc[n], 0, 0, 0);
            oacc[n] = __builtin_amdgcn_mfma_f32_16x16x32_bf16(pf1, vf1, oacc[n], 0, 0, 0);
        }
    }

#pragma unroll
    for (int r = 0; r < 4; ++r) {
        const int row = quad * 4 + r;
#pragma unroll
        for (int n = 0; n < 4; ++n) Olds[wv][row][n * 16 + i16] = oacc[n][r];
        if (i16 == 0) { mlds[wv][row] = m4[r]; llds[wv][row] = l4[r]; }
    }
    __syncthreads();
    if (wv == 0) {
#pragma unroll
        for (int r = 0; r < 4; ++r) {
            const int row = quad * 4 + r;
            const float mm0 = mlds[0][row], mm1 = mlds[1][row];
            const float mm2 = mlds[2][row], mm3 = mlds[3][row];
            const float ms = fmaxf(fmaxf(mm0, mm1), fmaxf(mm2, mm3));
            const float w0 = __expf(mm0 - ms), w1 = __expf(mm1 - ms);
            const float w2 = __expf(mm2 - ms), w3 = __expf(mm3 - ms);
            const float ll = llds[0][row] * w0 + llds[1][row] * w1
                           + llds[2][row] * w2 + llds[3][row] * w3;
            const float sc = 8.0f / ll;
            float* orow = O + (base + row0 + row) * DH;
#pragma unroll
            for (int n = 0; n < 4; ++n) {
                const int col = n * 16 + i16;
                orow[col] = (Olds[0][row][col] * w0 + Olds[1][row][col] * w1
                           + Olds[2][row][col] * w2 + Olds[3][row][col] * w3) * sc;
            }
        }
    }
}

extern "C" void kernel_launch(void* const* d_in, const int* in_sizes, int n_in,
                              void* d_out, int out_size, void* d_ws, size_t ws_size,
                              hipStream_t stream) {
    const float* x  = (const float*)d_in[0];
    const float* Wq = (const float*)d_in[1];
    const float* bq = (const float*)d_in[2];
    const float* Wk = (const float*)d_in[3];
    const float* bk = (const float*)d_in[4];
    const float* Wv = (const float*)d_in[5];
    const float* bv = (const float*)d_in[6];

    const size_t N = (size_t)B * T * DH;        // 1M elements
    u16* Qh = (u16*)d_ws;
    u16* Ql = Qh + N;
    u16* Kh = Ql + N;
    u16* Kl = Kh + N;
    u16* Vt = Kl + N;                           // [B, 64, T] transposed
    u16* Wh = Vt + N;                           // [192, 512]
    u16* Wl = Wh + (size_t)192 * DEMB;

    convert_w<<<dim3(192 * DEMB / 256), dim3(256), 0, stream>>>(Wq, Wk, Wv, Wh, Wl);
    proj_mfma<<<dim3(B * T / 32), dim3(256), 0, stream>>>(
        x, Wh, Wl, bq, bk, bv, Qh, Ql, Kh, Kl, Vt);
    attn_mfma<<<dim3(B * (T / 16)), dim3(256), 0, stream>>>(
        Qh, Ql, Kh, Kl, Vt, (float*)d_out);
}

// Round 5
// 221.774 us; speedup vs baseline: 3.2973x; 1.1109x over previous
//
#include <hip/hip_runtime.h>
#include <hip/hip_bf16.h>
#include <math.h>

#define B 4
#define T 4096
#define DEMB 512
#define DH 64

typedef unsigned short u16;
typedef __attribute__((ext_vector_type(4))) float f32x4;
typedef __attribute__((ext_vector_type(8))) short bf16x8;

__device__ __forceinline__ u16 f2bf(float f) {
    union { float f; unsigned u; } v; v.f = f;
    const unsigned r = v.u + 0x7FFFu + ((v.u >> 16) & 1u);   // RNE; inputs finite
    return (u16)(r >> 16);
}
__device__ __forceinline__ float bf2f(u16 h) {
    union { unsigned u; float f; } v; v.u = ((unsigned)h) << 16;
    return v.f;
}

// ---------------------------------------------------------------------------
// W prepass: concat Wq|Wk|Wv -> [192][512], split into hi + residual-lo bf16.
// ---------------------------------------------------------------------------
__global__ __launch_bounds__(256) void convert_w(
    const float* __restrict__ Wq, const float* __restrict__ Wk,
    const float* __restrict__ Wv, u16* __restrict__ Wh, u16* __restrict__ Wl)
{
    const int idx = blockIdx.x * 256 + threadIdx.x;     // covers 192*512
    const int row = idx >> 9;
    const int k   = idx & 511;
    const float* W = row < 64 ? Wq : (row < 128 ? Wk : Wv);
    const float v = W[(row & 63) * DEMB + k];
    const u16 hi = f2bf(v);
    Wh[idx] = hi;
    Wl[idx] = f2bf(v - bf2f(hi));
}

// ---------------------------------------------------------------------------
// QKV projection, split-bf16 MFMA GEMM: [16384x512] x [512x192].
// 1024 blocks (16 x-rows each) = 4 blocks/CU, 4 waves = 16 waves/CU.
// All 4 waves share the 16-row A-fragments (LDS); wave wv owns n-tiles
// 3wv..3wv+2 (48 cols). Per tile: Ah*Bl + Al*Bh + Ah*Bh.
// ---------------------------------------------------------------------------
__global__ __launch_bounds__(256) void proj_mfma(
    const float* __restrict__ x,
    const u16* __restrict__ Wh, const u16* __restrict__ Wl,
    const float* __restrict__ bq, const float* __restrict__ bk,
    const float* __restrict__ bv,
    u16* __restrict__ Qh, u16* __restrict__ Ql,
    u16* __restrict__ Kh, u16* __restrict__ Kl,
    u16* __restrict__ Vt)
{
    __shared__ u16 xh[16][136], xl[16][136];   // stride 136: 2-way alias only

    const int tid  = threadIdx.x;
    const int wv   = tid >> 6;
    const int lane = tid & 63;
    const int i16  = lane & 15;
    const int quad = lane >> 4;
    const size_t r0 = (size_t)blockIdx.x * 16;

    f32x4 acc[3];
    const f32x4 zero = {0.f, 0.f, 0.f, 0.f};
#pragma unroll
    for (int n = 0; n < 3; ++n) acc[n] = zero;

    for (int cc = 0; cc < DEMB; cc += 128) {
        __syncthreads();                       // previous chunk's reads done
#pragma unroll
        for (int u = 0; u < 2; ++u) {
            const int idx = tid + 256 * u;     // 0..511 float4s
            const int row = idx >> 5, c4 = idx & 31;
            const float4 v = *(const float4*)(x + (r0 + row) * DEMB + cc + c4 * 4);
            const u16 h0 = f2bf(v.x), h1 = f2bf(v.y), h2 = f2bf(v.z), h3 = f2bf(v.w);
            ushort4 hv = {h0, h1, h2, h3};
            ushort4 lv = {f2bf(v.x - bf2f(h0)), f2bf(v.y - bf2f(h1)),
                          f2bf(v.z - bf2f(h2)), f2bf(v.w - bf2f(h3))};
            *(ushort4*)&xh[row][c4 * 4] = hv;
            *(ushort4*)&xl[row][c4 * 4] = lv;
        }
        __syncthreads();

#pragma unroll
        for (int kk = 0; kk < 128; kk += 32) {
            const bf16x8 ah = *(const bf16x8*)&xh[i16][kk + quad * 8];
            const bf16x8 al = *(const bf16x8*)&xl[i16][kk + quad * 8];
#pragma unroll
            for (int n = 0; n < 3; ++n) {
                const int tile = wv * 3 + n;
                const size_t woff = (size_t)(tile * 16 + i16) * DEMB
                                  + cc + kk + quad * 8;
                const bf16x8 bh = *(const bf16x8*)(Wh + woff);
                const bf16x8 bl = *(const bf16x8*)(Wl + woff);
                acc[n] = __builtin_amdgcn_mfma_f32_16x16x32_bf16(ah, bl, acc[n], 0, 0, 0);
                acc[n] = __builtin_amdgcn_mfma_f32_16x16x32_bf16(al, bh, acc[n], 0, 0, 0);
                acc[n] = __builtin_amdgcn_mfma_f32_16x16x32_bf16(ah, bh, acc[n], 0, 0, 0);
            }
        }
    }

    const size_t bb = r0 / T;                  // uniform per block (16 | 4096)
    const size_t t0 = r0 - bb * T;
#pragma unroll
    for (int n = 0; n < 3; ++n) {
        const int tile = wv * 3 + n;           // 0..11
        const int m = tile >> 2;               // 0=Q,1=K,2=V (wave-uniform)
        const int h = (tile & 3) * 16 + i16;
        const float bias = (m == 0 ? bq : (m == 1 ? bk : bv))[h];
#pragma unroll
        for (int r = 0; r < 4; ++r) {
            const int row = quad * 4 + r;
            const float v = acc[n][r] + bias;
            const size_t grow = r0 + row;
            if (m == 2) {
                Vt[(bb * DH + h) * T + t0 + row] = f2bf(v);
            } else {
                const u16 hi = f2bf(v);
                const u16 lo = f2bf(v - bf2f(hi));
                if (m == 0) { Qh[grow * DH + h] = hi; Ql[grow * DH + h] = lo; }
                else        { Kh[grow * DH + h] = hi; Kl[grow * DH + h] = lo; }
            }
        }
    }
}

// ---------------------------------------------------------------------------
// Causal flash attention, split-bf16 QK^T, PERFECTLY BALANCED blocks:
// block = pair of q-groups (p, 255-p) -> exactly 65 chunks of work each.
// 512 blocks x 8 waves (512 thr); each wave 8-way k-splits each group
// sequentially (A then B), flash-combining 8 partials per group via LDS
// (A flushed before B so Olds is reused -> 56 KB -> 2 blocks/CU).
// ---------------------------------------------------------------------------
__global__ __launch_bounds__(512, 4) void attn_mfma(
    const u16* __restrict__ Qhp, const u16* __restrict__ Qlp,
    const u16* __restrict__ Khp, const u16* __restrict__ Klp,
    const u16* __restrict__ Vt, float* __restrict__ O)
{
    __shared__ u16   Plds[8][16][80];
    __shared__ float Olds[8][16][68];
    __shared__ float mlds[8][16], llds[8][16];

    const int tid  = threadIdx.x;
    const int wv   = tid >> 6;      // 0..7
    const int lane = tid & 63;
    const int i16  = lane & 15;
    const int quad = lane >> 4;

    const int bb = blockIdx.x >> 7;             // batch
    const int p  = blockIdx.x & 127;
    const size_t base = (size_t)bb * T;
    const f32x4 zero = {0.f, 0.f, 0.f, 0.f};

    for (int gsel = 0; gsel < 2; ++gsel) {
        const int g = gsel == 0 ? p : 255 - p;  // pair sums to 65 chunks
        const int row0 = g * 16;
        const int nchunks = (g >> 2) + 1;

        const u16* qrowh = Qhp + (base + row0 + i16) * DH;
        const u16* qrowl = Qlp + (base + row0 + i16) * DH;
        const bf16x8 qh0 = *(const bf16x8*)(qrowh + quad * 8);
        const bf16x8 qh1 = *(const bf16x8*)(qrowh + 32 + quad * 8);
        const bf16x8 ql0 = *(const bf16x8*)(qrowl + quad * 8);
        const bf16x8 ql1 = *(const bf16x8*)(qrowl + 32 + quad * 8);

        f32x4 oacc[4];
        float m4[4], l4[4];
#pragma unroll
        for (int n = 0; n < 4; ++n) oacc[n] = zero;
#pragma unroll
        for (int r = 0; r < 4; ++r) { m4[r] = -INFINITY; l4[r] = 0.f; }

        for (int c = wv; c < nchunks; c += 8) {
            const int kb = c << 6;
            f32x4 s[4];
#pragma unroll
            for (int n = 0; n < 4; ++n) {
                const u16* krh = Khp + (base + kb + n * 16 + i16) * DH;
                const u16* krl = Klp + (base + kb + n * 16 + i16) * DH;
                const bf16x8 kh0 = *(const bf16x8*)(krh + quad * 8);
                const bf16x8 kh1 = *(const bf16x8*)(krh + 32 + quad * 8);
                const bf16x8 kl0 = *(const bf16x8*)(krl + quad * 8);
                const bf16x8 kl1 = *(const bf16x8*)(krl + 32 + quad * 8);
                f32x4 a = __builtin_amdgcn_mfma_f32_16x16x32_bf16(qh0, kl0, zero, 0, 0, 0);
                a = __builtin_amdgcn_mfma_f32_16x16x32_bf16(qh1, kl1, a, 0, 0, 0);
                a = __builtin_amdgcn_mfma_f32_16x16x32_bf16(ql0, kh0, a, 0, 0, 0);
                a = __builtin_amdgcn_mfma_f32_16x16x32_bf16(ql1, kh1, a, 0, 0, 0);
                a = __builtin_amdgcn_mfma_f32_16x16x32_bf16(qh0, kh0, a, 0, 0, 0);
                a = __builtin_amdgcn_mfma_f32_16x16x32_bf16(qh1, kh1, a, 0, 0, 0);
                s[n] = a;
            }
            if (c == nchunks - 1) {             // diagonal chunk: causal mask
#pragma unroll
                for (int n = 0; n < 4; ++n)
#pragma unroll
                    for (int r = 0; r < 4; ++r)
                        if (kb + n * 16 + i16 > row0 + quad * 4 + r)
                            s[n][r] = -INFINITY;
            }
            float alpha[4];
#pragma unroll
            for (int r = 0; r < 4; ++r) {
                float mx = fmaxf(fmaxf(s[0][r], s[1][r]), fmaxf(s[2][r], s[3][r]));
                mx = fmaxf(mx, __shfl_xor(mx, 1, 64));
                mx = fmaxf(mx, __shfl_xor(mx, 2, 64));
                mx = fmaxf(mx, __shfl_xor(mx, 4, 64));
                mx = fmaxf(mx, __shfl_xor(mx, 8, 64));
                const float mnew = fmaxf(m4[r], mx);
                alpha[r] = __expf(m4[r] - mnew);
                m4[r] = mnew;
#pragma unroll
                for (int n = 0; n < 4; ++n) s[n][r] = __expf(s[n][r] - mnew);
            }
            float sum4[4] = {0.f, 0.f, 0.f, 0.f};
#pragma unroll
            for (int n = 0; n < 4; ++n)
#pragma unroll
                for (int r = 0; r < 4; ++r) {
                    const u16 pb = f2bf(s[n][r]);
                    Plds[wv][quad * 4 + r][n * 16 + i16] = pb;
                    sum4[r] += bf2f(pb);
                    oacc[n][r] *= alpha[r];
                }
#pragma unroll
            for (int r = 0; r < 4; ++r) {
                float sum = sum4[r];
                sum += __shfl_xor(sum, 1, 64);
                sum += __shfl_xor(sum, 2, 64);
                sum += __shfl_xor(sum, 4, 64);
                sum += __shfl_xor(sum, 8, 64);
                l4[r] = l4[r] * alpha[r] + sum;
            }
            const bf16x8 pf0 = *(const bf16x8*)&Plds[wv][i16][quad * 8];
            const bf16x8 pf1 = *(const bf16x8*)&Plds[wv][i16][32 + quad * 8];
#pragma unroll
            for (int n = 0; n < 4; ++n) {
                const u16* vrow = Vt + ((size_t)bb * DH + n * 16 + i16) * T + kb;
                const bf16x8 vf0 = *(const bf16x8*)(vrow + quad * 8);
                const bf16x8 vf1 = *(const bf16x8*)(vrow + 32 + quad * 8);
                oacc[n] = __builtin_amdgcn_mfma_f32_16x16x32_bf16(pf0, vf0, oacc[n], 0, 0, 0);
                oacc[n] = __builtin_amdgcn_mfma_f32_16x16x32_bf16(pf1, vf1, oacc[n], 0, 0, 0);
            }
        }

        // ---- flash-combine: 8 wave-partials for this group
#pragma unroll
        for (int r = 0; r < 4; ++r) {
            const int row = quad * 4 + r;
#pragma unroll
            for (int n = 0; n < 4; ++n) Olds[wv][row][n * 16 + i16] = oacc[n][r];
            if (i16 == 0) { mlds[wv][row] = m4[r]; llds[wv][row] = l4[r]; }
        }
        __syncthreads();
        {
            const int row = tid >> 5;            // 0..15
            const int c0  = (tid & 31) * 2;      // cols c0, c0+1
            float ms = -INFINITY;
#pragma unroll
            for (int jj = 0; jj < 8; ++jj) ms = fmaxf(ms, mlds[jj][row]);
            float ll = 0.f, o0 = 0.f, o1 = 0.f;
#pragma unroll
            for (int jj = 0; jj < 8; ++jj) {
                const float w = __expf(mlds[jj][row] - ms);
                ll += llds[jj][row] * w;
                o0 += Olds[jj][row][c0] * w;
                o1 += Olds[jj][row][c0 + 1] * w;
            }
            const float sc = 8.0f / ll;          // post-softmax * sqrt(64)
            float* orow = O + (base + row0 + row) * DH;
            orow[c0]     = o0 * sc;
            orow[c0 + 1] = o1 * sc;
        }
        __syncthreads();                         // Olds reused by next group
    }
}

extern "C" void kernel_launch(void* const* d_in, const int* in_sizes, int n_in,
                              void* d_out, int out_size, void* d_ws, size_t ws_size,
                              hipStream_t stream) {
    const float* x  = (const float*)d_in[0];
    const float* Wq = (const float*)d_in[1];
    const float* bq = (const float*)d_in[2];
    const float* Wk = (const float*)d_in[3];
    const float* bk = (const float*)d_in[4];
    const float* Wv = (const float*)d_in[5];
    const float* bv = (const float*)d_in[6];

    const size_t N = (size_t)B * T * DH;        // 1M elements
    u16* Qh = (u16*)d_ws;
    u16* Ql = Qh + N;
    u16* Kh = Ql + N;
    u16* Kl = Kh + N;
    u16* Vt = Kl + N;                           // [B, 64, T] transposed
    u16* Wh = Vt + N;                           // [192, 512]
    u16* Wl = Wh + (size_t)192 * DEMB;

    convert_w<<<dim3(192 * DEMB / 256), dim3(256), 0, stream>>>(Wq, Wk, Wv, Wh, Wl);
    proj_mfma<<<dim3(B * T / 16), dim3(256), 0, stream>>>(
        x, Wh, Wl, bq, bk, bv, Qh, Ql, Kh, Kl, Vt);
    attn_mfma<<<dim3(B * 128), dim3(512), 0, stream>>>(
        Qh, Ql, Kh, Kl, Vt, (float*)d_out);
}

// Round 6
// 217.763 us; speedup vs baseline: 3.3580x; 1.0184x over previous
//
#include <hip/hip_runtime.h>
#include <hip/hip_bf16.h>
#include <math.h>

#define B 4
#define T 4096
#define DEMB 512
#define DH 64
#define NSPLIT 8

typedef unsigned short u16;
typedef __attribute__((ext_vector_type(4))) float f32x4;
typedef __attribute__((ext_vector_type(8))) short bf16x8;

__device__ __forceinline__ u16 f2bf(float f) {
    union { float f; unsigned u; } v; v.f = f;
    const unsigned r = v.u + 0x7FFFu + ((v.u >> 16) & 1u);   // RNE; inputs finite
    return (u16)(r >> 16);
}
__device__ __forceinline__ float bf2f(u16 h) {
    union { unsigned u; float f; } v; v.u = ((unsigned)h) << 16;
    return v.f;
}

// ---------------------------------------------------------------------------
// W prepass: concat Wq|Wk|Wv -> [192][512], split into hi + residual-lo bf16.
// ---------------------------------------------------------------------------
__global__ __launch_bounds__(256) void convert_w(
    const float* __restrict__ Wq, const float* __restrict__ Wk,
    const float* __restrict__ Wv, u16* __restrict__ Wh, u16* __restrict__ Wl)
{
    const int idx = blockIdx.x * 256 + threadIdx.x;     // covers 192*512
    const int row = idx >> 9;
    const int k   = idx & 511;
    const float* W = row < 64 ? Wq : (row < 128 ? Wk : Wv);
    const float v = W[(row & 63) * DEMB + k];
    const u16 hi = f2bf(v);
    Wh[idx] = hi;
    Wl[idx] = f2bf(v - bf2f(hi));
}

// ---------------------------------------------------------------------------
// QKV projection, split-bf16 MFMA GEMM: [16384x512] x [512x192].
// 512 blocks x 4 waves; block = 32 x-rows, all 192 cols.
// Per 64-k chunk: stage x (fp32) + W hi/lo slice into LDS; inner loop is
// pure LDS b128 + MFMA (no global loads on the critical path).
// Wave = (row-group rg = wv&1) x (n-half nh = wv>>1, 6 of 12 n-tiles).
// Per tile: Ah*Bl + Al*Bh + Ah*Bh  (xl*wl ~2^-17, dropped).
// ---------------------------------------------------------------------------
__global__ __launch_bounds__(256) void proj_mfma(
    const float* __restrict__ x,
    const u16* __restrict__ Whg, const u16* __restrict__ Wlg,
    const float* __restrict__ bq, const float* __restrict__ bk,
    const float* __restrict__ bv,
    u16* __restrict__ Qh, u16* __restrict__ Ql,
    u16* __restrict__ Kh, u16* __restrict__ Kl,
    u16* __restrict__ Vt)
{
    __shared__ float xs[32][68];          // 8704 B  (stride 272 B: 16B-aligned)
    __shared__ u16 Whs[192][72];          // 27648 B (stride 144 B: 16B-aligned)
    __shared__ u16 Wls[192][72];          // 27648 B  -> total 64000 B

    const int tid  = threadIdx.x;
    const int wv   = tid >> 6;
    const int lane = tid & 63;
    const int i16  = lane & 15;
    const int quad = lane >> 4;
    const int rg   = wv & 1;              // row-group (16 rows)
    const int nh   = wv >> 1;             // n-half (6 tiles of 16 cols)
    const size_t r0 = (size_t)blockIdx.x * 32;

    f32x4 acc[6];
    const f32x4 zero = {0.f, 0.f, 0.f, 0.f};
#pragma unroll
    for (int n = 0; n < 6; ++n) acc[n] = zero;

    for (int cc = 0; cc < DEMB; cc += 64) {
        __syncthreads();
        // stage x: 32 rows x 64 cols fp32 = 512 float4
#pragma unroll
        for (int u = 0; u < 2; ++u) {
            const int idx = tid + 256 * u;
            const int row = idx >> 4, c4 = idx & 15;
            *(float4*)&xs[row][c4 * 4] =
                *(const float4*)(x + (r0 + row) * DEMB + cc + c4 * 4);
        }
        // stage W hi/lo: 192 rows x 64 cols u16 = 3072 ushort4 each
#pragma unroll
        for (int u = 0; u < 12; ++u) {
            const int idx = tid + 256 * u;
            const int row = idx >> 4, c4 = idx & 15;
            *(ushort4*)&Whs[row][c4 * 4] =
                *(const ushort4*)(Whg + (size_t)row * DEMB + cc + c4 * 4);
            *(ushort4*)&Wls[row][c4 * 4] =
                *(const ushort4*)(Wlg + (size_t)row * DEMB + cc + c4 * 4);
        }
        __syncthreads();

#pragma unroll
        for (int kk = 0; kk < 2; ++kk) {
            // A-fragment: 8 fp32 from LDS -> split hi/lo bf16 in registers
            const float4 a0 = *(const float4*)&xs[rg * 16 + i16][kk * 32 + quad * 8];
            const float4 a1 = *(const float4*)&xs[rg * 16 + i16][kk * 32 + quad * 8 + 4];
            float af[8] = {a0.x, a0.y, a0.z, a0.w, a1.x, a1.y, a1.z, a1.w};
            bf16x8 ah, al;
#pragma unroll
            for (int j = 0; j < 8; ++j) {
                const u16 hi = f2bf(af[j]);
                ah[j] = (short)hi;
                al[j] = (short)f2bf(af[j] - bf2f(hi));
            }
#pragma unroll
            for (int n = 0; n < 6; ++n) {
                const int tile = nh * 6 + n;
                const bf16x8 bh = *(const bf16x8*)&Whs[tile * 16 + i16][kk * 32 + quad * 8];
                const bf16x8 bl = *(const bf16x8*)&Wls[tile * 16 + i16][kk * 32 + quad * 8];
                acc[n] = __builtin_amdgcn_mfma_f32_16x16x32_bf16(ah, bl, acc[n], 0, 0, 0);
                acc[n] = __builtin_amdgcn_mfma_f32_16x16x32_bf16(al, bh, acc[n], 0, 0, 0);
                acc[n] = __builtin_amdgcn_mfma_f32_16x16x32_bf16(ah, bh, acc[n], 0, 0, 0);
            }
        }
    }

    const size_t bb = r0 / T;                  // uniform per block (32 | 4096)
    const size_t t0 = r0 - bb * T;
#pragma unroll
    for (int n = 0; n < 6; ++n) {
        const int tile = nh * 6 + n;           // 0..11
        const int col  = tile * 16 + i16;      // 0..191
        const int m = col >> 6, h = col & 63;
        const float bias = (m == 0 ? bq : (m == 1 ? bk : bv))[h];
#pragma unroll
        for (int r = 0; r < 4; ++r) {
            const int row = rg * 16 + quad * 4 + r;
            const float v = acc[n][r] + bias;
            const size_t grow = r0 + row;
            if (m == 2) {
                Vt[(bb * DH + h) * T + t0 + row] = f2bf(v);
            } else {
                const u16 hi = f2bf(v);
                const u16 lo = f2bf(v - bf2f(hi));
                if (m == 0) { Qh[grow * DH + h] = hi; Ql[grow * DH + h] = lo; }
                else        { Kh[grow * DH + h] = hi; Kl[grow * DH + h] = lo; }
            }
        }
    }
}

// ---------------------------------------------------------------------------
// Attention pass 1: partials. Grid (b, tile p, split s) = 4 x 32 x 8.
// Block = 8 waves (512 thr) on one 128-row q-tile; chunks c = s, s+8, ...
// K/V chunk (Kh/Kl/V, 24 KB) staged in LDS ONCE per block-chunk, shared by
// all 8 waves -> global K/V traffic drops ~8x vs per-wave streaming.
// Per-wave online softmax (split-bf16 QK^T, P LDS roundtrip, PV MFMA);
// partial (O, m, l) written to scratch; pass 2 combines the 8 splits.
// ---------------------------------------------------------------------------
__global__ __launch_bounds__(512) void attn_partial(
    const u16* __restrict__ Qhp, const u16* __restrict__ Qlp,
    const u16* __restrict__ Khp, const u16* __restrict__ Klp,
    const u16* __restrict__ Vt,
    float* __restrict__ Opart, float* __restrict__ mpart,
    float* __restrict__ lpart)
{
    __shared__ u16 Ksh[64][72], Ksl[64][72], Vs[64][72];   // 27648 B
    __shared__ u16 Plds[8][16][72];                        // 18432 B

    const int tid  = threadIdx.x;
    const int wv   = tid >> 6;      // 0..7
    const int lane = tid & 63;
    const int i16  = lane & 15;
    const int quad = lane >> 4;

    const int s  = blockIdx.x & 7;
    const int p  = 31 - ((blockIdx.x >> 3) & 31);   // biggest tiles first
    const int bb = blockIdx.x >> 8;
    const size_t base = (size_t)bb * T;
    const int row0w = p * 128 + wv * 16;            // this wave's first q-row
    const int cmax  = 2 * p + 1;

    const u16* qrh = Qhp + (base + row0w + i16) * DH;
    const u16* qrl = Qlp + (base + row0w + i16) * DH;
    const bf16x8 qh0 = *(const bf16x8*)(qrh + quad * 8);
    const bf16x8 qh1 = *(const bf16x8*)(qrh + 32 + quad * 8);
    const bf16x8 ql0 = *(const bf16x8*)(qrl + quad * 8);
    const bf16x8 ql1 = *(const bf16x8*)(qrl + 32 + quad * 8);

    f32x4 oacc[4];
    float m4[4], l4[4];
    const f32x4 zero = {0.f, 0.f, 0.f, 0.f};
#pragma unroll
    for (int n = 0; n < 4; ++n) oacc[n] = zero;
#pragma unroll
    for (int r = 0; r < 4; ++r) { m4[r] = -INFINITY; l4[r] = 0.f; }

    for (int c = s; c <= cmax; c += NSPLIT) {
        const int kb = c << 6;
        __syncthreads();                 // previous chunk fully consumed
        // ---- stage Kh/Kl (64x64 u16) and V (Vt rows, 64x64 u16)
#pragma unroll
        for (int u = 0; u < 2; ++u) {
            const int idx = tid + 512 * u;          // 0..1023
            const int row = idx >> 4, c4 = idx & 15;
            *(ushort4*)&Ksh[row][c4 * 4] =
                *(const ushort4*)(Khp + (base + kb + row) * DH + c4 * 4);
            *(ushort4*)&Ksl[row][c4 * 4] =
                *(const ushort4*)(Klp + (base + kb + row) * DH + c4 * 4);
            *(ushort4*)&Vs[row][c4 * 4] =
                *(const ushort4*)(Vt + ((size_t)bb * DH + row) * T + kb + c4 * 4);
        }
        __syncthreads();

        if (kb <= row0w + 15) {          // else fully masked for this wave
            f32x4 sc[4];
#pragma unroll
            for (int n = 0; n < 4; ++n) {
                const bf16x8 kh0 = *(const bf16x8*)&Ksh[n * 16 + i16][quad * 8];
                const bf16x8 kh1 = *(const bf16x8*)&Ksh[n * 16 + i16][32 + quad * 8];
                const bf16x8 kl0 = *(const bf16x8*)&Ksl[n * 16 + i16][quad * 8];
                const bf16x8 kl1 = *(const bf16x8*)&Ksl[n * 16 + i16][32 + quad * 8];
                f32x4 a = __builtin_amdgcn_mfma_f32_16x16x32_bf16(qh0, kl0, zero, 0, 0, 0);
                a = __builtin_amdgcn_mfma_f32_16x16x32_bf16(qh1, kl1, a, 0, 0, 0);
                a = __builtin_amdgcn_mfma_f32_16x16x32_bf16(ql0, kh0, a, 0, 0, 0);
                a = __builtin_amdgcn_mfma_f32_16x16x32_bf16(ql1, kh1, a, 0, 0, 0);
                a = __builtin_amdgcn_mfma_f32_16x16x32_bf16(qh0, kh0, a, 0, 0, 0);
                a = __builtin_amdgcn_mfma_f32_16x16x32_bf16(qh1, kh1, a, 0, 0, 0);
                sc[n] = a;
            }
            if (kb + 63 > row0w) {       // diagonal: causal mask
#pragma unroll
                for (int n = 0; n < 4; ++n)
#pragma unroll
                    for (int r = 0; r < 4; ++r)
                        if (kb + n * 16 + i16 > row0w + quad * 4 + r)
                            sc[n][r] = -INFINITY;
            }
            float alpha[4];
#pragma unroll
            for (int r = 0; r < 4; ++r) {
                float mx = fmaxf(fmaxf(sc[0][r], sc[1][r]), fmaxf(sc[2][r], sc[3][r]));
                mx = fmaxf(mx, __shfl_xor(mx, 1, 64));
                mx = fmaxf(mx, __shfl_xor(mx, 2, 64));
                mx = fmaxf(mx, __shfl_xor(mx, 4, 64));
                mx = fmaxf(mx, __shfl_xor(mx, 8, 64));
                const float mnew = fmaxf(m4[r], mx);   // finite: kb <= row0w
                alpha[r] = __expf(m4[r] - mnew);
                m4[r] = mnew;
#pragma unroll
                for (int n = 0; n < 4; ++n) sc[n][r] = __expf(sc[n][r] - mnew);
            }
            float sum4[4] = {0.f, 0.f, 0.f, 0.f};
#pragma unroll
            for (int n = 0; n < 4; ++n)
#pragma unroll
                for (int r = 0; r < 4; ++r) {
                    const u16 pb = f2bf(sc[n][r]);
                    Plds[wv][quad * 4 + r][n * 16 + i16] = pb;
                    sum4[r] += bf2f(pb);
                    oacc[n][r] *= alpha[r];
                }
#pragma unroll
            for (int r = 0; r < 4; ++r) {
                float sum = sum4[r];
                sum += __shfl_xor(sum, 1, 64);
                sum += __shfl_xor(sum, 2, 64);
                sum += __shfl_xor(sum, 4, 64);
                sum += __shfl_xor(sum, 8, 64);
                l4[r] = l4[r] * alpha[r] + sum;
            }
            const bf16x8 pf0 = *(const bf16x8*)&Plds[wv][i16][quad * 8];
            const bf16x8 pf1 = *(const bf16x8*)&Plds[wv][i16][32 + quad * 8];
#pragma unroll
            for (int n = 0; n < 4; ++n) {
                const bf16x8 vf0 = *(const bf16x8*)&Vs[n * 16 + i16][quad * 8];
                const bf16x8 vf1 = *(const bf16x8*)&Vs[n * 16 + i16][32 + quad * 8];
                oacc[n] = __builtin_amdgcn_mfma_f32_16x16x32_bf16(pf0, vf0, oacc[n], 0, 0, 0);
                oacc[n] = __builtin_amdgcn_mfma_f32_16x16x32_bf16(pf1, vf1, oacc[n], 0, 0, 0);
            }
        }
    }

    // ---- write partial (O rows 128 x 64 fp32, m, l) for this block
    float* Ob = Opart + (size_t)blockIdx.x * (128 * 64);
#pragma unroll
    for (int r = 0; r < 4; ++r) {
        const int row = wv * 16 + quad * 4 + r;
#pragma unroll
        for (int n = 0; n < 4; ++n) Ob[row * 64 + n * 16 + i16] = oacc[n][r];
        if (i16 == 0) {
            mpart[(size_t)blockIdx.x * 128 + row] = m4[r];
            lpart[(size_t)blockIdx.x * 128 + row] = l4[r];
        }
    }
}

// ---------------------------------------------------------------------------
// Attention pass 2: combine 8 split-partials per q-tile.
// Grid (b, p) = 128 blocks x 256 thr.
// ---------------------------------------------------------------------------
__global__ __launch_bounds__(256) void attn_combine(
    const float* __restrict__ Opart, const float* __restrict__ mpart,
    const float* __restrict__ lpart, float* __restrict__ O)
{
    __shared__ float ws[128][8];
    __shared__ float scl[128];

    const int tid = threadIdx.x;
    const int p  = blockIdx.x & 31;
    const int bb = blockIdx.x >> 5;
    const int prev = 31 - p;                         // undo biggest-first map
    const size_t pb0 = ((size_t)bb * 32 + prev) * 8; // first split block id

    if (tid < 128) {
        const int row = tid;
        float m[NSPLIT];
        float M = -INFINITY;
#pragma unroll
        for (int q = 0; q < NSPLIT; ++q) {
            m[q] = mpart[(pb0 + q) * 128 + row];
            M = fmaxf(M, m[q]);
        }
        float L = 0.f;
#pragma unroll
        for (int q = 0; q < NSPLIT; ++q) {
            const float w = __expf(m[q] - M);        // M finite (s=0 nonempty)
            ws[row][q] = w;
            L += w * lpart[(pb0 + q) * 128 + row];
        }
        scl[row] = 8.0f / L;                         // post-softmax * sqrt(64)
    }
    __syncthreads();

    const int col = tid & 63;
    const int rg  = tid >> 6;                        // 0..3
    for (int j = 0; j < 32; ++j) {
        const int row = rg + j * 4;
        float acc = 0.f;
#pragma unroll
        for (int q = 0; q < NSPLIT; ++q)
            acc += ws[row][q] * Opart[(pb0 + q) * (128 * 64) + row * 64 + col];
        O[((size_t)bb * T + p * 128 + row) * DH + col] = acc * scl[row];
    }
}

extern "C" void kernel_launch(void* const* d_in, const int* in_sizes, int n_in,
                              void* d_out, int out_size, void* d_ws, size_t ws_size,
                              hipStream_t stream) {
    const float* x  = (const float*)d_in[0];
    const float* Wq = (const float*)d_in[1];
    const float* bq = (const float*)d_in[2];
    const float* Wk = (const float*)d_in[3];
    const float* bk = (const float*)d_in[4];
    const float* Wv = (const float*)d_in[5];
    const float* bv = (const float*)d_in[6];

    const size_t N  = (size_t)B * T * DH;       // 1,048,576
    const size_t WN = (size_t)192 * DEMB;       // 98,304
    u16* Qh = (u16*)d_ws;
    u16* Ql = Qh + N;
    u16* Kh = Ql + N;
    u16* Kl = Kh + N;
    u16* Vt = Kl + N;                           // [B, 64, T]
    u16* Wh = Vt + N;
    u16* Wl = Wh + WN;
    float* Opart = (float*)(Wl + WN);           // 16B-aligned (offset 10878976)
    float* mpart = Opart + (size_t)1024 * 128 * 64;
    float* lpart = mpart + (size_t)1024 * 128;

    convert_w<<<dim3(192 * DEMB / 256), dim3(256), 0, stream>>>(Wq, Wk, Wv, Wh, Wl);
    proj_mfma<<<dim3(B * T / 32), dim3(256), 0, stream>>>(
        x, Wh, Wl, bq, bk, bv, Qh, Ql, Kh, Kl, Vt);
    attn_partial<<<dim3(B * 32 * NSPLIT), dim3(512), 0, stream>>>(
        Qh, Ql, Kh, Kl, Vt, Opart, mpart, lpart);
    attn_combine<<<dim3(B * 32), dim3(256), 0, stream>>>(
        Opart, mpart, lpart, (float*)d_out);
}

// Round 7
// 171.969 us; speedup vs baseline: 4.2522x; 1.2663x over previous
//
#include <hip/hip_runtime.h>
#include <hip/hip_fp16.h>
#include <math.h>

#define B 4
#define T 4096
#define DEMB 512
#define DH 64
#define NSPLIT 8

typedef _Float16 f16;
typedef __attribute__((ext_vector_type(8))) _Float16 f16x8;
typedef __attribute__((ext_vector_type(4))) float f32x4;

// ---------------------------------------------------------------------------
// W prepass: concat Wq|Wk|Wv -> [192][512] fp16.
// ---------------------------------------------------------------------------
__global__ __launch_bounds__(256) void convert_w(
    const float* __restrict__ Wq, const float* __restrict__ Wk,
    const float* __restrict__ Wv, f16* __restrict__ Wf)
{
    const int idx = blockIdx.x * 256 + threadIdx.x;     // covers 192*512
    const int row = idx >> 9;
    const int k   = idx & 511;
    const float* W = row < 64 ? Wq : (row < 128 ? Wk : Wv);
    Wf[idx] = (f16)W[(row & 63) * DEMB + k];
}

// ---------------------------------------------------------------------------
// QKV projection, fp16 MFMA GEMM: [16384x512] x [512x192].
// 512 blocks x 4 waves; block = 32 x-rows, all 192 cols; k-chunks of 128.
// Stage x (fp32->fp16) + W fp16 slice in LDS; inner loop pure LDS b128+MFMA.
// Wave = (row-group rg = wv&1) x (n-half nh = wv>>1, 6 of 12 n-tiles).
// ---------------------------------------------------------------------------
__global__ __launch_bounds__(256) void proj_mfma(
    const float* __restrict__ x, const f16* __restrict__ Wfg,
    const float* __restrict__ bq, const float* __restrict__ bk,
    const float* __restrict__ bv,
    f16* __restrict__ Qf, f16* __restrict__ Kf, f16* __restrict__ Vt)
{
    __shared__ f16 xs[32][136];           // 8704 B  (272 B rows: 2-way alias)
    __shared__ f16 Ws[192][136];          // 52224 B -> total ~59.5 KB

    const int tid  = threadIdx.x;
    const int wv   = tid >> 6;
    const int lane = tid & 63;
    const int i16  = lane & 15;
    const int quad = lane >> 4;
    const int rg   = wv & 1;              // 16-row group
    const int nh   = wv >> 1;             // n-half (6 tiles)
    const size_t r0 = (size_t)blockIdx.x * 32;

    f32x4 acc[6];
    const f32x4 zero = {0.f, 0.f, 0.f, 0.f};
#pragma unroll
    for (int n = 0; n < 6; ++n) acc[n] = zero;

    for (int cc = 0; cc < DEMB; cc += 128) {
        __syncthreads();
        // stage x: 32 rows x 128 cols fp32 -> fp16 (512 groups of 8)
#pragma unroll
        for (int u = 0; u < 2; ++u) {
            const int idx = tid + 256 * u;          // 0..511
            const int row = idx >> 4, g = idx & 15;
            const float4 a = *(const float4*)(x + (r0 + row) * DEMB + cc + g * 8);
            const float4 b = *(const float4*)(x + (r0 + row) * DEMB + cc + g * 8 + 4);
            f16x8 h = {(f16)a.x, (f16)a.y, (f16)a.z, (f16)a.w,
                       (f16)b.x, (f16)b.y, (f16)b.z, (f16)b.w};
            *(f16x8*)&xs[row][g * 8] = h;
        }
        // stage W: 192 rows x 128 cols fp16 (3072 groups of 8)
#pragma unroll
        for (int u = 0; u < 12; ++u) {
            const int idx = tid + 256 * u;          // 0..3071
            const int row = idx >> 4, g = idx & 15;
            *(f16x8*)&Ws[row][g * 8] =
                *(const f16x8*)(Wfg + (size_t)row * DEMB + cc + g * 8);
        }
        __syncthreads();

#pragma unroll
        for (int kk = 0; kk < 4; ++kk) {
            const f16x8 af = *(const f16x8*)&xs[rg * 16 + i16][kk * 32 + quad * 8];
#pragma unroll
            for (int n = 0; n < 6; ++n) {
                const f16x8 bf = *(const f16x8*)&Ws[(nh * 6 + n) * 16 + i16][kk * 32 + quad * 8];
                acc[n] = __builtin_amdgcn_mfma_f32_16x16x32_f16(af, bf, acc[n], 0, 0, 0);
            }
        }
    }

    const size_t bb = r0 / T;                  // uniform per block (32 | 4096)
    const size_t t0 = r0 - bb * T;
#pragma unroll
    for (int n = 0; n < 6; ++n) {
        const int col = (nh * 6 + n) * 16 + i16;    // 0..191
        const int m = col >> 6, h = col & 63;
        const float bias = (m == 0 ? bq : (m == 1 ? bk : bv))[h];
#pragma unroll
        for (int r = 0; r < 4; ++r) {
            const int row = rg * 16 + quad * 4 + r;
            const f16 v = (f16)(acc[n][r] + bias);
            const size_t grow = r0 + row;
            if (m == 0)      Qf[grow * DH + h] = v;
            else if (m == 1) Kf[grow * DH + h] = v;
            else             Vt[(bb * DH + h) * T + t0 + row] = v;
        }
    }
}

// ---------------------------------------------------------------------------
// Attention pass 1: partials, fp16 MFMA. Grid (b, tile p, split s) = 4x32x8.
// Block = 8 waves (512 thr) on one 128-row q-tile; chunks c = s, s+8, ...
// K/V chunk (16 KB) staged in LDS once per block-chunk, shared by 8 waves.
// __launch_bounds__(512,8): 4 blocks/CU = 32 waves/CU.
// ---------------------------------------------------------------------------
__global__ __launch_bounds__(512, 8) void attn_partial(
    const f16* __restrict__ Qf, const f16* __restrict__ Kf,
    const f16* __restrict__ Vt,
    f16* __restrict__ Opart, float* __restrict__ mpart,
    float* __restrict__ lpart)
{
    __shared__ f16 Ks[64][72], Vs[64][72];      // 18432 B
    __shared__ f16 Plds[8][16][72];             // 18432 B -> 36 KB total

    const int tid  = threadIdx.x;
    const int wv   = tid >> 6;      // 0..7
    const int lane = tid & 63;
    const int i16  = lane & 15;
    const int quad = lane >> 4;

    const int s  = blockIdx.x & 7;
    const int p  = 31 - ((blockIdx.x >> 3) & 31);   // biggest tiles first
    const int bb = blockIdx.x >> 8;
    const size_t base = (size_t)bb * T;
    const int row0w = p * 128 + wv * 16;            // this wave's first q-row
    const int cmax  = 2 * p + 1;

    const f16* qr = Qf + (base + row0w + i16) * DH;
    const f16x8 qf0 = *(const f16x8*)(qr + quad * 8);
    const f16x8 qf1 = *(const f16x8*)(qr + 32 + quad * 8);

    f32x4 oacc[4];
    float m4[4], l4[4];
    const f32x4 zero = {0.f, 0.f, 0.f, 0.f};
#pragma unroll
    for (int n = 0; n < 4; ++n) oacc[n] = zero;
#pragma unroll
    for (int r = 0; r < 4; ++r) { m4[r] = -INFINITY; l4[r] = 0.f; }

    const int srow = tid >> 3, sg = tid & 7;        // staging coords

    for (int c = s; c <= cmax; c += NSPLIT) {
        const int kb = c << 6;
        __syncthreads();                 // previous chunk fully consumed
        *(f16x8*)&Ks[srow][sg * 8] =
            *(const f16x8*)(Kf + (base + kb + srow) * DH + sg * 8);
        *(f16x8*)&Vs[srow][sg * 8] =
            *(const f16x8*)(Vt + ((size_t)bb * DH + srow) * T + kb + sg * 8);
        __syncthreads();

        if (kb <= row0w + 15) {          // else fully masked for this wave
            f32x4 sc[4];
#pragma unroll
            for (int n = 0; n < 4; ++n) {
                const f16x8 kf0 = *(const f16x8*)&Ks[n * 16 + i16][quad * 8];
                const f16x8 kf1 = *(const f16x8*)&Ks[n * 16 + i16][32 + quad * 8];
                f32x4 a = __builtin_amdgcn_mfma_f32_16x16x32_f16(qf0, kf0, zero, 0, 0, 0);
                a = __builtin_amdgcn_mfma_f32_16x16x32_f16(qf1, kf1, a, 0, 0, 0);
                sc[n] = a;
            }
            if (kb + 63 > row0w) {       // diagonal: causal mask
#pragma unroll
                for (int n = 0; n < 4; ++n)
#pragma unroll
                    for (int r = 0; r < 4; ++r)
                        if (kb + n * 16 + i16 > row0w + quad * 4 + r)
                            sc[n][r] = -INFINITY;
            }
            float alpha[4];
#pragma unroll
            for (int r = 0; r < 4; ++r) {
                float mx = fmaxf(fmaxf(sc[0][r], sc[1][r]), fmaxf(sc[2][r], sc[3][r]));
                mx = fmaxf(mx, __shfl_xor(mx, 1, 64));
                mx = fmaxf(mx, __shfl_xor(mx, 2, 64));
                mx = fmaxf(mx, __shfl_xor(mx, 4, 64));
                mx = fmaxf(mx, __shfl_xor(mx, 8, 64));
                const float mnew = fmaxf(m4[r], mx);   // finite: kb <= row0w
                alpha[r] = __expf(m4[r] - mnew);
                m4[r] = mnew;
#pragma unroll
                for (int n = 0; n < 4; ++n) sc[n][r] = __expf(sc[n][r] - mnew);
            }
            // P -> fp16 LDS (l sums the ROUNDED p: numerator/denominator match)
            float sum4[4] = {0.f, 0.f, 0.f, 0.f};
#pragma unroll
            for (int n = 0; n < 4; ++n)
#pragma unroll
                for (int r = 0; r < 4; ++r) {
                    const f16 pb = (f16)sc[n][r];
                    Plds[wv][quad * 4 + r][n * 16 + i16] = pb;
                    sum4[r] += (float)pb;
                    oacc[n][r] *= alpha[r];
                }
#pragma unroll
            for (int r = 0; r < 4; ++r) {
                float sum = sum4[r];
                sum += __shfl_xor(sum, 1, 64);
                sum += __shfl_xor(sum, 2, 64);
                sum += __shfl_xor(sum, 4, 64);
                sum += __shfl_xor(sum, 8, 64);
                l4[r] = l4[r] * alpha[r] + sum;
            }
            const f16x8 pf0 = *(const f16x8*)&Plds[wv][i16][quad * 8];
            const f16x8 pf1 = *(const f16x8*)&Plds[wv][i16][32 + quad * 8];
#pragma unroll
            for (int n = 0; n < 4; ++n) {
                const f16x8 vf0 = *(const f16x8*)&Vs[n * 16 + i16][quad * 8];
                const f16x8 vf1 = *(const f16x8*)&Vs[n * 16 + i16][32 + quad * 8];
                oacc[n] = __builtin_amdgcn_mfma_f32_16x16x32_f16(pf0, vf0, oacc[n], 0, 0, 0);
                oacc[n] = __builtin_amdgcn_mfma_f32_16x16x32_f16(pf1, vf1, oacc[n], 0, 0, 0);
            }
        }
    }

    // ---- write partial (O 128x64 fp16, m, l) for this block
    f16* Ob = Opart + (size_t)blockIdx.x * (128 * 64);
#pragma unroll
    for (int r = 0; r < 4; ++r) {
        const int row = wv * 16 + quad * 4 + r;
#pragma unroll
        for (int n = 0; n < 4; ++n) Ob[row * 64 + n * 16 + i16] = (f16)oacc[n][r];
        if (i16 == 0) {
            mpart[(size_t)blockIdx.x * 128 + row] = m4[r];
            lpart[(size_t)blockIdx.x * 128 + row] = l4[r];
        }
    }
}

// ---------------------------------------------------------------------------
// Attention pass 2: combine 8 split-partials per q-tile.
// ---------------------------------------------------------------------------
__global__ __launch_bounds__(256) void attn_combine(
    const f16* __restrict__ Opart, const float* __restrict__ mpart,
    const float* __restrict__ lpart, float* __restrict__ O)
{
    __shared__ float ws[128][NSPLIT];
    __shared__ float scl[128];

    const int tid = threadIdx.x;
    const int p  = blockIdx.x & 31;
    const int bb = blockIdx.x >> 5;
    const int prev = 31 - p;                         // undo biggest-first map
    const size_t pb0 = ((size_t)bb * 32 + prev) * NSPLIT;

    if (tid < 128) {
        const int row = tid;
        float m[NSPLIT];
        float M = -INFINITY;
#pragma unroll
        for (int q = 0; q < NSPLIT; ++q) {
            m[q] = mpart[(pb0 + q) * 128 + row];
            M = fmaxf(M, m[q]);
        }
        float L = 0.f;
#pragma unroll
        for (int q = 0; q < NSPLIT; ++q) {
            const float w = __expf(m[q] - M);        // M finite (s=0 nonempty)
            ws[row][q] = w;
            L += w * lpart[(pb0 + q) * 128 + row];
        }
        scl[row] = 8.0f / L;                         // post-softmax * sqrt(64)
    }
    __syncthreads();

    const int col = tid & 63;
    const int rg  = tid >> 6;                        // 0..3
    for (int j = 0; j < 32; ++j) {
        const int row = rg + j * 4;
        float acc = 0.f;
#pragma unroll
        for (int q = 0; q < NSPLIT; ++q)
            acc += ws[row][q] * (float)Opart[(pb0 + q) * (128 * 64) + row * 64 + col];
        O[((size_t)bb * T + p * 128 + row) * DH + col] = acc * scl[row];
    }
}

extern "C" void kernel_launch(void* const* d_in, const int* in_sizes, int n_in,
                              void* d_out, int out_size, void* d_ws, size_t ws_size,
                              hipStream_t stream) {
    const float* x  = (const float*)d_in[0];
    const float* Wq = (const float*)d_in[1];
    const float* bq = (const float*)d_in[2];
    const float* Wk = (const float*)d_in[3];
    const float* bk = (const float*)d_in[4];
    const float* Wv = (const float*)d_in[5];
    const float* bv = (const float*)d_in[6];

    const size_t N  = (size_t)B * T * DH;       // 1,048,576
    f16* Qf = (f16*)d_ws;
    f16* Kf = Qf + N;
    f16* Vt = Kf + N;                           // [B, 64, T]
    f16* Wf = Vt + N;                           // [192, 512]
    f16* Opart = Wf + (size_t)192 * DEMB;       // 1024 x 128 x 64 fp16
    float* mpart = (float*)(Opart + (size_t)1024 * 128 * 64);
    float* lpart = mpart + (size_t)1024 * 128;

    convert_w<<<dim3(192 * DEMB / 256), dim3(256), 0, stream>>>(Wq, Wk, Wv, Wf);
    proj_mfma<<<dim3(B * T / 32), dim3(256), 0, stream>>>(
        x, Wf, bq, bk, bv, Qf, Kf, Vt);
    attn_partial<<<dim3(B * 32 * NSPLIT), dim3(512), 0, stream>>>(
        Qf, Kf, Vt, Opart, mpart, lpart);
    attn_combine<<<dim3(B * 32), dim3(256), 0, stream>>>(
        Opart, mpart, lpart, (float*)d_out);
}

// Round 8
// 165.067 us; speedup vs baseline: 4.4301x; 1.0418x over previous
//
#include <hip/hip_runtime.h>
#include <hip/hip_fp16.h>
#include <math.h>

#define B 4
#define T 4096
#define DEMB 512
#define DH 64
#define NSPLIT 16
#define NPTILE 16            // 256-row q-tiles per batch

typedef _Float16 f16;
typedef __attribute__((ext_vector_type(4))) _Float16 f16x4;
typedef __attribute__((ext_vector_type(8))) _Float16 f16x8;
typedef __attribute__((ext_vector_type(4))) float f32x4;

// ---------------------------------------------------------------------------
// W prepass: concat Wq|Wk|Wv -> [192][512] fp16.
// ---------------------------------------------------------------------------
__global__ __launch_bounds__(256) void convert_w(
    const float* __restrict__ Wq, const float* __restrict__ Wk,
    const float* __restrict__ Wv, f16* __restrict__ Wf)
{
    const int idx = blockIdx.x * 256 + threadIdx.x;     // covers 192*512
    const int row = idx >> 9;
    const int k   = idx & 511;
    const float* W = row < 64 ? Wq : (row < 128 ? Wk : Wv);
    Wf[idx] = (f16)W[(row & 63) * DEMB + k];
}

// ---------------------------------------------------------------------------
// QKV projection, fp16 MFMA GEMM: [16384x512] x [512x192].
// 256 blocks x 8 waves; block = 64 x-rows, all 192 cols; k-chunks of 128.
// Wave = (rg = wv>>1: 16-row group) x (nh = wv&1: 6 of 12 n-tiles).
// Inner loop pure LDS b128 + MFMA.
// ---------------------------------------------------------------------------
__global__ __launch_bounds__(512) void proj_mfma(
    const float* __restrict__ x, const f16* __restrict__ Wfg,
    const float* __restrict__ bq, const float* __restrict__ bk,
    const float* __restrict__ bv,
    f16* __restrict__ Qf, f16* __restrict__ Kf, f16* __restrict__ Vt)
{
    __shared__ f16 xs[64][136];           // 17408 B (272 B rows)
    __shared__ f16 Ws[192][136];          // 52224 B -> ~70 KB total

    const int tid  = threadIdx.x;
    const int wv   = tid >> 6;
    const int lane = tid & 63;
    const int i16  = lane & 15;
    const int quad = lane >> 4;
    const int rg   = wv >> 1;             // 16-row group 0..3
    const int nh   = wv & 1;              // n-half (6 tiles)
    const size_t r0 = (size_t)blockIdx.x * 64;

    f32x4 acc[6];
    const f32x4 zero = {0.f, 0.f, 0.f, 0.f};
#pragma unroll
    for (int n = 0; n < 6; ++n) acc[n] = zero;

    for (int cc = 0; cc < DEMB; cc += 128) {
        __syncthreads();
        // stage x: 64 rows x 128 cols fp32 -> fp16 (1024 groups of 8)
#pragma unroll
        for (int u = 0; u < 2; ++u) {
            const int idx = tid + 512 * u;
            const int row = idx >> 4, g = idx & 15;
            const float4 a = *(const float4*)(x + (r0 + row) * DEMB + cc + g * 8);
            const float4 b = *(const float4*)(x + (r0 + row) * DEMB + cc + g * 8 + 4);
            f16x8 h = {(f16)a.x, (f16)a.y, (f16)a.z, (f16)a.w,
                       (f16)b.x, (f16)b.y, (f16)b.z, (f16)b.w};
            *(f16x8*)&xs[row][g * 8] = h;
        }
        // stage W: 192 rows x 128 cols fp16 (3072 groups of 8)
#pragma unroll
        for (int u = 0; u < 6; ++u) {
            const int idx = tid + 512 * u;
            const int row = idx >> 4, g = idx & 15;
            *(f16x8*)&Ws[row][g * 8] =
                *(const f16x8*)(Wfg + (size_t)row * DEMB + cc + g * 8);
        }
        __syncthreads();

#pragma unroll
        for (int kk = 0; kk < 4; ++kk) {
            const f16x8 af = *(const f16x8*)&xs[rg * 16 + i16][kk * 32 + quad * 8];
#pragma unroll
            for (int n = 0; n < 6; ++n) {
                const f16x8 bf = *(const f16x8*)&Ws[(nh * 6 + n) * 16 + i16][kk * 32 + quad * 8];
                acc[n] = __builtin_amdgcn_mfma_f32_16x16x32_f16(af, bf, acc[n], 0, 0, 0);
            }
        }
    }

    const size_t bb = r0 / T;                  // uniform per block (64 | 4096)
    const size_t t0 = r0 - bb * T;
#pragma unroll
    for (int n = 0; n < 6; ++n) {
        const int col = (nh * 6 + n) * 16 + i16;    // 0..191
        const int m = col >> 6, h = col & 63;
        const float bias = (m == 0 ? bq : (m == 1 ? bk : bv))[h];
#pragma unroll
        for (int r = 0; r < 4; ++r) {
            const int row = rg * 16 + quad * 4 + r;
            const f16 v = (f16)(acc[n][r] + bias);
            const size_t grow = r0 + row;
            if (m == 0)      Qf[grow * DH + h] = v;
            else if (m == 1) Kf[grow * DH + h] = v;
            else             Vt[(bb * DH + h) * T + t0 + row] = v;
        }
    }
}

// ---------------------------------------------------------------------------
// Attention pass 1 (TRANSPOSED layout to minimize DS-pipe work).
//   St = K·Q^T  (C/D: col=lane&15 = q, row = k-local)  -> per-lane q-row
//   softmax stats: 15 VALU + 2 shuffles (xor 16, 32) per group
//   P^T packed f16x4 -> 4 ds_write_b64; alpha applied to O^T with NO shuffle
//   O^T = V^T·P^T (A-frag = Vt rows from LDS, B-frag = P^T rows, b128)
// Grid (b, ptile, split) = 4 x 16 x 16 = 1024 blocks; block = 8 waves,
// each wave owns q-groups wv and wv+8 (2 x 16 rows) sharing K/V fragments.
// ---------------------------------------------------------------------------
__global__ __launch_bounds__(512, 4) void attn_partial(
    const f16* __restrict__ Qf, const f16* __restrict__ Kf,
    const f16* __restrict__ Vt,
    f16* __restrict__ Opart, float* __restrict__ mpart,
    float* __restrict__ lpart)
{
    __shared__ f16 Ks[64][72], Vs[64][72];      // 18432 B
    __shared__ f16 Pl[8][16][72];               // 18432 B -> 36 KB total

    const int tid  = threadIdx.x;
    const int wv   = tid >> 6;      // 0..7
    const int lane = tid & 63;
    const int i16  = lane & 15;
    const int quad = lane >> 4;

    const int s    = blockIdx.x & 15;
    const int p    = 15 - ((blockIdx.x >> 4) & 15);   // biggest tiles first
    const int bb   = blockIdx.x >> 8;
    const size_t base = (size_t)bb * T;
    const int row0 = p * 256;
    const int cmax = 4 * p + 3;
    const int rowg0 = row0 + wv * 16;
    const int rowg1 = row0 + (wv + 8) * 16;

    // Q B-frags (held in registers for the whole kernel)
    f16x8 qf00, qf01, qf10, qf11;
    {
        const f16* q0 = Qf + (base + rowg0 + i16) * DH;
        const f16* q1 = Qf + (base + rowg1 + i16) * DH;
        qf00 = *(const f16x8*)(q0 + quad * 8);
        qf01 = *(const f16x8*)(q0 + 32 + quad * 8);
        qf10 = *(const f16x8*)(q1 + quad * 8);
        qf11 = *(const f16x8*)(q1 + 32 + quad * 8);
    }

    f32x4 oacc[2][4];
    float mm[2] = {-INFINITY, -INFINITY}, ll[2] = {0.f, 0.f};
    const f32x4 zero = {0.f, 0.f, 0.f, 0.f};
#pragma unroll
    for (int j = 0; j < 2; ++j)
#pragma unroll
        for (int n = 0; n < 4; ++n) oacc[j][n] = zero;

    const int srow = tid >> 3, sg = tid & 7;

    for (int c = s; c <= cmax; c += NSPLIT) {
        const int kb = c << 6;
        __syncthreads();
        *(f16x8*)&Ks[srow][sg * 8] =
            *(const f16x8*)(Kf + (base + kb + srow) * DH + sg * 8);
        *(f16x8*)&Vs[srow][sg * 8] =
            *(const f16x8*)(Vt + ((size_t)bb * DH + srow) * T + kb + sg * 8);
        __syncthreads();

        const bool a0 = kb <= rowg0, a1 = kb <= rowg1;  // a0 => a1
        if (!a1) continue;                  // barriers at loop top stay uniform

        // ---- St = K·Q^T, shared K A-frags
        f32x4 st[2][4];
#pragma unroll
        for (int kt = 0; kt < 4; ++kt) {
            const f16x8 kf0 = *(const f16x8*)&Ks[kt * 16 + i16][quad * 8];
            const f16x8 kf1 = *(const f16x8*)&Ks[kt * 16 + i16][32 + quad * 8];
            if (a0) {
                f32x4 a = __builtin_amdgcn_mfma_f32_16x16x32_f16(kf0, qf00, zero, 0, 0, 0);
                st[0][kt] = __builtin_amdgcn_mfma_f32_16x16x32_f16(kf1, qf01, a, 0, 0, 0);
            }
            {
                f32x4 a = __builtin_amdgcn_mfma_f32_16x16x32_f16(kf0, qf10, zero, 0, 0, 0);
                st[1][kt] = __builtin_amdgcn_mfma_f32_16x16x32_f16(kf1, qf11, a, 0, 0, 0);
            }
        }
        // ---- per-group softmax + P^T write + P^T read-back
        f16x8 pf[2][2];
#pragma unroll
        for (int j = 0; j < 2; ++j) {
            if (j == 0 && !a0) continue;
            const int rowg = j == 0 ? rowg0 : rowg1;
            if (kb + 63 > rowg) {           // diagonal chunk: causal mask
#pragma unroll
                for (int kt = 0; kt < 4; ++kt)
#pragma unroll
                    for (int r = 0; r < 4; ++r)
                        if (kb + kt * 16 + quad * 4 + r > rowg + i16)
                            st[j][kt][r] = -INFINITY;
            }
            float mx = -INFINITY;
#pragma unroll
            for (int kt = 0; kt < 4; ++kt)
#pragma unroll
                for (int r = 0; r < 4; ++r) mx = fmaxf(mx, st[j][kt][r]);
            mx = fmaxf(mx, __shfl_xor(mx, 16, 64));
            mx = fmaxf(mx, __shfl_xor(mx, 32, 64));
            const float mnew = fmaxf(mm[j], mx);        // finite: kb <= rowg
            const float alpha = __expf(mm[j] - mnew);
            mm[j] = mnew;
            float sum = 0.f;
#pragma unroll
            for (int kt = 0; kt < 4; ++kt) {
                f16x4 pk;
#pragma unroll
                for (int r = 0; r < 4; ++r) {
                    const f16 pb = (f16)__expf(st[j][kt][r] - mnew);
                    pk[r] = pb;
                    sum += (float)pb;       // l sums ROUNDED p (matches PV)
                }
                *(f16x4*)&Pl[wv][i16][kt * 16 + quad * 4] = pk;
            }
            sum += __shfl_xor(sum, 16, 64);
            sum += __shfl_xor(sum, 32, 64);
            ll[j] = ll[j] * alpha + sum;
#pragma unroll
            for (int n = 0; n < 4; ++n) oacc[j][n] *= alpha;   // col=q=i16: no shuffle
            pf[j][0] = *(const f16x8*)&Pl[wv][i16][quad * 8];
            pf[j][1] = *(const f16x8*)&Pl[wv][i16][32 + quad * 8];
        }
        // ---- O^T += V^T·P^T, shared V A-frags
#pragma unroll
        for (int mt = 0; mt < 4; ++mt) {
            const f16x8 vf0 = *(const f16x8*)&Vs[mt * 16 + i16][quad * 8];
            const f16x8 vf1 = *(const f16x8*)&Vs[mt * 16 + i16][32 + quad * 8];
            if (a0) {
                oacc[0][mt] = __builtin_amdgcn_mfma_f32_16x16x32_f16(vf0, pf[0][0], oacc[0][mt], 0, 0, 0);
                oacc[0][mt] = __builtin_amdgcn_mfma_f32_16x16x32_f16(vf1, pf[0][1], oacc[0][mt], 0, 0, 0);
            }
            oacc[1][mt] = __builtin_amdgcn_mfma_f32_16x16x32_f16(vf0, pf[1][0], oacc[1][mt], 0, 0, 0);
            oacc[1][mt] = __builtin_amdgcn_mfma_f32_16x16x32_f16(vf1, pf[1][1], oacc[1][mt], 0, 0, 0);
        }
    }

    // ---- epilogue: O^T regs -> Opart rows (lane i16 = q)
    f16* Ob = Opart + (size_t)blockIdx.x * (256 * 64);
#pragma unroll
    for (int j = 0; j < 2; ++j) {
        const int prow = (wv + 8 * j) * 16 + i16;       // tile-local q-row
#pragma unroll
        for (int mt = 0; mt < 4; ++mt) {
            f16x4 pk = {(f16)oacc[j][mt][0], (f16)oacc[j][mt][1],
                        (f16)oacc[j][mt][2], (f16)oacc[j][mt][3]};
            *(f16x4*)&Ob[prow * 64 + mt * 16 + quad * 4] = pk;
        }
        if (quad == 0) {
            mpart[(size_t)blockIdx.x * 256 + prow] = mm[j];
            lpart[(size_t)blockIdx.x * 256 + prow] = ll[j];
        }
    }
}

// ---------------------------------------------------------------------------
// Attention pass 2: combine 16 split-partials. Grid (b, p, rowquarter)=256.
// ---------------------------------------------------------------------------
__global__ __launch_bounds__(256) void attn_combine(
    const f16* __restrict__ Opart, const float* __restrict__ mpart,
    const float* __restrict__ lpart, float* __restrict__ O)
{
    __shared__ float ws[64][NSPLIT + 1];
    __shared__ float scl[64];

    const int tid = threadIdx.x;
    const int rh  = blockIdx.x & 3;
    const int p   = (blockIdx.x >> 2) & 15;
    const int bb  = blockIdx.x >> 6;
    const size_t pb0 = (size_t)bb * 256 + (15 - p) * 16;  // split block ids
    const int r0c = rh * 64;

    if (tid < 64) {
        const int row = r0c + tid;
        float m[NSPLIT];
        float M = -INFINITY;
#pragma unroll
        for (int q = 0; q < NSPLIT; ++q) {
            m[q] = mpart[(pb0 + q) * 256 + row];
            M = fmaxf(M, m[q]);
        }
        float L = 0.f;
#pragma unroll
        for (int q = 0; q < NSPLIT; ++q) {
            const float w = __expf(m[q] - M);       // M finite (s=0 nonempty)
            ws[tid][q] = w;
            L += w * lpart[(pb0 + q) * 256 + row];
        }
        scl[tid] = 8.0f / L;                        // post-softmax * sqrt(64)
    }
    __syncthreads();

    const int col = tid & 63;
    const int rg  = tid >> 6;                       // 0..3
#pragma unroll 4
    for (int jj = 0; jj < 16; ++jj) {
        const int rowl = rg + 4 * jj;               // 0..63
        const int row  = r0c + rowl;
        float acc = 0.f;
#pragma unroll
        for (int q = 0; q < NSPLIT; ++q)
            acc += ws[rowl][q] * (float)Opart[(pb0 + q) * (256 * 64) + row * 64 + col];
        O[((size_t)bb * T + p * 256 + row) * DH + col] = acc * scl[rowl];
    }
}

extern "C" void kernel_launch(void* const* d_in, const int* in_sizes, int n_in,
                              void* d_out, int out_size, void* d_ws, size_t ws_size,
                              hipStream_t stream) {
    const float* x  = (const float*)d_in[0];
    const float* Wq = (const float*)d_in[1];
    const float* bq = (const float*)d_in[2];
    const float* Wk = (const float*)d_in[3];
    const float* bk = (const float*)d_in[4];
    const float* Wv = (const float*)d_in[5];
    const float* bv = (const float*)d_in[6];

    const size_t N  = (size_t)B * T * DH;       // 1,048,576
    f16* Qf = (f16*)d_ws;
    f16* Kf = Qf + N;
    f16* Vt = Kf + N;                           // [B, 64, T]
    f16* Wf = Vt + N;                           // [192, 512]
    f16* Opart = Wf + (size_t)192 * DEMB;       // 1024 x 256 x 64 fp16
    float* mpart = (float*)(Opart + (size_t)1024 * 256 * 64);
    float* lpart = mpart + (size_t)1024 * 256;

    convert_w<<<dim3(192 * DEMB / 256), dim3(256), 0, stream>>>(Wq, Wk, Wv, Wf);
    proj_mfma<<<dim3(B * T / 64), dim3(512), 0, stream>>>(
        x, Wf, bq, bk, bv, Qf, Kf, Vt);
    attn_partial<<<dim3(B * NPTILE * NSPLIT), dim3(512), 0, stream>>>(
        Qf, Kf, Vt, Opart, mpart, lpart);
    attn_combine<<<dim3(B * NPTILE * 4), dim3(256), 0, stream>>>(
        Opart, mpart, lpart, (float*)d_out);
}

// Round 9
// 133.175 us; speedup vs baseline: 5.4909x; 1.2395x over previous
//
#include <hip/hip_runtime.h>
#include <hip/hip_fp16.h>
#include <math.h>

#define B 4
#define T 4096
#define DEMB 512
#define DH 64
#define NSPLIT 16
#define NPTILE 16            // 256-row q-tiles per batch

typedef _Float16 f16;
typedef __attribute__((ext_vector_type(4))) _Float16 f16x4;
typedef __attribute__((ext_vector_type(8))) _Float16 f16x8;
typedef __attribute__((ext_vector_type(4))) float f32x4;

// ---------------------------------------------------------------------------
// W prepass: concat Wq|Wk|Wv -> [192][512] fp16.
// ---------------------------------------------------------------------------
__global__ __launch_bounds__(256) void convert_w(
    const float* __restrict__ Wq, const float* __restrict__ Wk,
    const float* __restrict__ Wv, f16* __restrict__ Wf)
{
    const int idx = blockIdx.x * 256 + threadIdx.x;     // covers 192*512
    const int row = idx >> 9;
    const int k   = idx & 511;
    const float* W = row < 64 ? Wq : (row < 128 ? Wk : Wv);
    Wf[idx] = (f16)W[(row & 63) * DEMB + k];
}

// ---------------------------------------------------------------------------
// QKV projection, fp16 MFMA GEMM: [16384x512] x [512x192].
// 256 blocks x 8 waves; block = 64 x-rows, all 192 cols; k-chunks of 128.
// Wave = (rg = wv>>1: 16-row group) x (nh = wv&1: 6 of 12 n-tiles).
// Inner loop pure LDS b128 + MFMA.
// ---------------------------------------------------------------------------
__global__ __launch_bounds__(512) void proj_mfma(
    const float* __restrict__ x, const f16* __restrict__ Wfg,
    const float* __restrict__ bq, const float* __restrict__ bk,
    const float* __restrict__ bv,
    f16* __restrict__ Qf, f16* __restrict__ Kf, f16* __restrict__ Vt)
{
    __shared__ f16 xs[64][136];           // 17408 B (272 B rows)
    __shared__ f16 Ws[192][136];          // 52224 B -> ~70 KB total

    const int tid  = threadIdx.x;
    const int wv   = tid >> 6;
    const int lane = tid & 63;
    const int i16  = lane & 15;
    const int quad = lane >> 4;
    const int rg   = wv >> 1;             // 16-row group 0..3
    const int nh   = wv & 1;              // n-half (6 tiles)
    const size_t r0 = (size_t)blockIdx.x * 64;

    f32x4 acc[6];
    const f32x4 zero = {0.f, 0.f, 0.f, 0.f};
#pragma unroll
    for (int n = 0; n < 6; ++n) acc[n] = zero;

    for (int cc = 0; cc < DEMB; cc += 128) {
        __syncthreads();
        // stage x: 64 rows x 128 cols fp32 -> fp16 (1024 groups of 8)
#pragma unroll
        for (int u = 0; u < 2; ++u) {
            const int idx = tid + 512 * u;
            const int row = idx >> 4, g = idx & 15;
            const float4 a = *(const float4*)(x + (r0 + row) * DEMB + cc + g * 8);
            const float4 b = *(const float4*)(x + (r0 + row) * DEMB + cc + g * 8 + 4);
            f16x8 h = {(f16)a.x, (f16)a.y, (f16)a.z, (f16)a.w,
                       (f16)b.x, (f16)b.y, (f16)b.z, (f16)b.w};
            *(f16x8*)&xs[row][g * 8] = h;
        }
        // stage W: 192 rows x 128 cols fp16 (3072 groups of 8)
#pragma unroll
        for (int u = 0; u < 6; ++u) {
            const int idx = tid + 512 * u;
            const int row = idx >> 4, g = idx & 15;
            *(f16x8*)&Ws[row][g * 8] =
                *(const f16x8*)(Wfg + (size_t)row * DEMB + cc + g * 8);
        }
        __syncthreads();

#pragma unroll
        for (int kk = 0; kk < 4; ++kk) {
            const f16x8 af = *(const f16x8*)&xs[rg * 16 + i16][kk * 32 + quad * 8];
#pragma unroll
            for (int n = 0; n < 6; ++n) {
                const f16x8 bf = *(const f16x8*)&Ws[(nh * 6 + n) * 16 + i16][kk * 32 + quad * 8];
                acc[n] = __builtin_amdgcn_mfma_f32_16x16x32_f16(af, bf, acc[n], 0, 0, 0);
            }
        }
    }

    const size_t bb = r0 / T;                  // uniform per block (64 | 4096)
    const size_t t0 = r0 - bb * T;
#pragma unroll
    for (int n = 0; n < 6; ++n) {
        const int col = (nh * 6 + n) * 16 + i16;    // 0..191
        const int m = col >> 6, h = col & 63;
        const float bias = (m == 0 ? bq : (m == 1 ? bk : bv))[h];
#pragma unroll
        for (int r = 0; r < 4; ++r) {
            const int row = rg * 16 + quad * 4 + r;
            const f16 v = (f16)(acc[n][r] + bias);
            const size_t grow = r0 + row;
            if (m == 0)      Qf[grow * DH + h] = v;
            else if (m == 1) Kf[grow * DH + h] = v;
            else             Vt[(bb * DH + h) * T + t0 + row] = v;
        }
    }
}

// ---------------------------------------------------------------------------
// Attention pass 1 (TRANSPOSED layout to minimize DS-pipe work).
//   St = K·Q^T  (C/D: col=lane&15 = q, row = k-local)  -> per-lane q-row
//   softmax stats: 15 VALU + 2 shuffles (xor 16, 32) per group
//   P^T packed f16x4 -> 4 ds_write_b64; alpha applied to O^T with NO shuffle
//   O^T = V^T·P^T (A-frag = Vt rows from LDS, B-frag = P^T rows, b128)
// Grid (b, ptile, split) = 4 x 16 x 16 = 1024 blocks; block = 8 waves,
// each wave owns q-groups wv and wv+8 (2 x 16 rows) sharing K/V fragments.
// ---------------------------------------------------------------------------
__global__ __launch_bounds__(512, 4) void attn_partial(
    const f16* __restrict__ Qf, const f16* __restrict__ Kf,
    const f16* __restrict__ Vt,
    f16* __restrict__ Opart, float* __restrict__ mpart,
    float* __restrict__ lpart)
{
    __shared__ f16 Ks[64][72], Vs[64][72];      // 18432 B
    __shared__ f16 Pl[8][16][72];               // 18432 B -> 36 KB total

    const int tid  = threadIdx.x;
    const int wv   = tid >> 6;      // 0..7
    const int lane = tid & 63;
    const int i16  = lane & 15;
    const int quad = lane >> 4;

    const int s    = blockIdx.x & 15;
    const int p    = 15 - ((blockIdx.x >> 4) & 15);   // biggest tiles first
    const int bb   = blockIdx.x >> 8;
    const size_t base = (size_t)bb * T;
    const int row0 = p * 256;
    const int cmax = 4 * p + 3;
    const int rowg0 = row0 + wv * 16;
    const int rowg1 = row0 + (wv + 8) * 16;

    // Q B-frags (held in registers for the whole kernel)
    f16x8 qf00, qf01, qf10, qf11;
    {
        const f16* q0 = Qf + (base + rowg0 + i16) * DH;
        const f16* q1 = Qf + (base + rowg1 + i16) * DH;
        qf00 = *(const f16x8*)(q0 + quad * 8);
        qf01 = *(const f16x8*)(q0 + 32 + quad * 8);
        qf10 = *(const f16x8*)(q1 + quad * 8);
        qf11 = *(const f16x8*)(q1 + 32 + quad * 8);
    }

    f32x4 oacc[2][4];
    float mm[2] = {-INFINITY, -INFINITY}, ll[2] = {0.f, 0.f};
    const f32x4 zero = {0.f, 0.f, 0.f, 0.f};
#pragma unroll
    for (int j = 0; j < 2; ++j)
#pragma unroll
        for (int n = 0; n < 4; ++n) oacc[j][n] = zero;

    const int srow = tid >> 3, sg = tid & 7;

    for (int c = s; c <= cmax; c += NSPLIT) {
        const int kb = c << 6;
        __syncthreads();
        *(f16x8*)&Ks[srow][sg * 8] =
            *(const f16x8*)(Kf + (base + kb + srow) * DH + sg * 8);
        *(f16x8*)&Vs[srow][sg * 8] =
            *(const f16x8*)(Vt + ((size_t)bb * DH + srow) * T + kb + sg * 8);
        __syncthreads();

        const bool a0 = kb <= rowg0, a1 = kb <= rowg1;  // a0 => a1
        if (!a1) continue;                  // barriers at loop top stay uniform

        // ---- St = K·Q^T, shared K A-frags
        f32x4 st[2][4];
#pragma unroll
        for (int kt = 0; kt < 4; ++kt) {
            const f16x8 kf0 = *(const f16x8*)&Ks[kt * 16 + i16][quad * 8];
            const f16x8 kf1 = *(const f16x8*)&Ks[kt * 16 + i16][32 + quad * 8];
            if (a0) {
                f32x4 a = __builtin_amdgcn_mfma_f32_16x16x32_f16(kf0, qf00, zero, 0, 0, 0);
                st[0][kt] = __builtin_amdgcn_mfma_f32_16x16x32_f16(kf1, qf01, a, 0, 0, 0);
            }
            {
                f32x4 a = __builtin_amdgcn_mfma_f32_16x16x32_f16(kf0, qf10, zero, 0, 0, 0);
                st[1][kt] = __builtin_amdgcn_mfma_f32_16x16x32_f16(kf1, qf11, a, 0, 0, 0);
            }
        }
        // ---- per-group softmax + P^T write + P^T read-back
        f16x8 pf[2][2];
#pragma unroll
        for (int j = 0; j < 2; ++j) {
            if (j == 0 && !a0) continue;
            const int rowg = j == 0 ? rowg0 : rowg1;
            if (kb + 63 > rowg) {           // diagonal chunk: causal mask
#pragma unroll
                for (int kt = 0; kt < 4; ++kt)
#pragma unroll
                    for (int r = 0; r < 4; ++r)
                        if (kb + kt * 16 + quad * 4 + r > rowg + i16)
                            st[j][kt][r] = -INFINITY;
            }
            float mx = -INFINITY;
#pragma unroll
            for (int kt = 0; kt < 4; ++kt)
#pragma unroll
                for (int r = 0; r < 4; ++r) mx = fmaxf(mx, st[j][kt][r]);
            mx = fmaxf(mx, __shfl_xor(mx, 16, 64));
            mx = fmaxf(mx, __shfl_xor(mx, 32, 64));
            const float mnew = fmaxf(mm[j], mx);        // finite: kb <= rowg
            const float alpha = __expf(mm[j] - mnew);
            mm[j] = mnew;
            float sum = 0.f;
#pragma unroll
            for (int kt = 0; kt < 4; ++kt) {
                f16x4 pk;
#pragma unroll
                for (int r = 0; r < 4; ++r) {
                    const f16 pb = (f16)__expf(st[j][kt][r] - mnew);
                    pk[r] = pb;
                    sum += (float)pb;       // l sums ROUNDED p (matches PV)
                }
                *(f16x4*)&Pl[wv][i16][kt * 16 + quad * 4] = pk;
            }
            sum += __shfl_xor(sum, 16, 64);
            sum += __shfl_xor(sum, 32, 64);
            ll[j] = ll[j] * alpha + sum;
#pragma unroll
            for (int n = 0; n < 4; ++n) oacc[j][n] *= alpha;   // col=q=i16: no shuffle
            pf[j][0] = *(const f16x8*)&Pl[wv][i16][quad * 8];
            pf[j][1] = *(const f16x8*)&Pl[wv][i16][32 + quad * 8];
        }
        // ---- O^T += V^T·P^T, shared V A-frags
#pragma unroll
        for (int mt = 0; mt < 4; ++mt) {
            const f16x8 vf0 = *(const f16x8*)&Vs[mt * 16 + i16][quad * 8];
            const f16x8 vf1 = *(const f16x8*)&Vs[mt * 16 + i16][32 + quad * 8];
            if (a0) {
                oacc[0][mt] = __builtin_amdgcn_mfma_f32_16x16x32_f16(vf0, pf[0][0], oacc[0][mt], 0, 0, 0);
                oacc[0][mt] = __builtin_amdgcn_mfma_f32_16x16x32_f16(vf1, pf[0][1], oacc[0][mt], 0, 0, 0);
            }
            oacc[1][mt] = __builtin_amdgcn_mfma_f32_16x16x32_f16(vf0, pf[1][0], oacc[1][mt], 0, 0, 0);
            oacc[1][mt] = __builtin_amdgcn_mfma_f32_16x16x32_f16(vf1, pf[1][1], oacc[1][mt], 0, 0, 0);
        }
    }

    // ---- epilogue: O^T regs -> Opart rows (lane i16 = q)
    f16* Ob = Opart + (size_t)blockIdx.x * (256 * 64);
#pragma unroll
    for (int j = 0; j < 2; ++j) {
        const int prow = (wv + 8 * j) * 16 + i16;       // tile-local q-row
#pragma unroll
        for (int mt = 0; mt < 4; ++mt) {
            f16x4 pk = {(f16)oacc[j][mt][0], (f16)oacc[j][mt][1],
                        (f16)oacc[j][mt][2], (f16)oacc[j][mt][3]};
            *(f16x4*)&Ob[prow * 64 + mt * 16 + quad * 4] = pk;
        }
        if (quad == 0) {
            mpart[(size_t)blockIdx.x * 256 + prow] = mm[j];
            lpart[(size_t)blockIdx.x * 256 + prow] = ll[j];
        }
    }
}

// ---------------------------------------------------------------------------
// Attention pass 2: combine split-partials.
// Grid (b, p, sub) = 4 x 16 x 16 = 1024 blocks (4/CU); block = 16 rows.
// Thread = (row, 4-col group): nact x f16x4 vector loads, float4 store.
// nact = min(16, 4p+4): splits beyond the causal frontier carry zero weight
// and are skipped (block-uniform bound).
// ---------------------------------------------------------------------------
__global__ __launch_bounds__(256) void attn_combine(
    const f16* __restrict__ Opart, const float* __restrict__ mpart,
    const float* __restrict__ lpart, float* __restrict__ O)
{
    __shared__ float ws[16][NSPLIT];
    __shared__ float scl[16];

    const int tid = threadIdx.x;
    const int sub = blockIdx.x & 15;                 // 16-row slice
    const int p   = (blockIdx.x >> 4) & 15;
    const int bb  = blockIdx.x >> 8;
    const size_t pb0 = (size_t)bb * 256 + (15 - p) * 16;   // split block ids
    const int nact = min(NSPLIT, 4 * p + 4);
    const int r0c  = sub * 16;

    if (tid < 16) {
        const int row = r0c + tid;
        float m[NSPLIT];
        float M = -INFINITY;
        for (int q = 0; q < nact; ++q) {
            m[q] = mpart[(pb0 + q) * 256 + row];
            M = fmaxf(M, m[q]);
        }
        float L = 0.f;
        for (int q = 0; q < nact; ++q) {
            const float w = __expf(m[q] - M);        // M finite (s<=cmax nonempty)
            ws[tid][q] = w;
            L += w * lpart[(pb0 + q) * 256 + row];
        }
        scl[tid] = 8.0f / L;                         // post-softmax * sqrt(64)
    }
    __syncthreads();

    const int rowl = tid >> 4;                       // 0..15
    const int c4   = tid & 15;                       // 4-col group
    const int row  = r0c + rowl;
    float a0 = 0.f, a1 = 0.f, a2 = 0.f, a3 = 0.f;
    for (int q = 0; q < nact; ++q) {
        const f16x4 v = *(const f16x4*)&Opart[(pb0 + q) * (256 * 64) + row * 64 + c4 * 4];
        const float w = ws[rowl][q];
        a0 += w * (float)v[0]; a1 += w * (float)v[1];
        a2 += w * (float)v[2]; a3 += w * (float)v[3];
    }
    const float s = scl[rowl];
    const float4 o = {a0 * s, a1 * s, a2 * s, a3 * s};
    *(float4*)&O[((size_t)bb * T + p * 256 + row) * DH + c4 * 4] = o;
}

extern "C" void kernel_launch(void* const* d_in, const int* in_sizes, int n_in,
                              void* d_out, int out_size, void* d_ws, size_t ws_size,
                              hipStream_t stream) {
    const float* x  = (const float*)d_in[0];
    const float* Wq = (const float*)d_in[1];
    const float* bq = (const float*)d_in[2];
    const float* Wk = (const float*)d_in[3];
    const float* bk = (const float*)d_in[4];
    const float* Wv = (const float*)d_in[5];
    const float* bv = (const float*)d_in[6];

    const size_t N  = (size_t)B * T * DH;       // 1,048,576
    f16* Qf = (f16*)d_ws;
    f16* Kf = Qf + N;
    f16* Vt = Kf + N;                           // [B, 64, T]
    f16* Wf = Vt + N;                           // [192, 512]
    f16* Opart = Wf + (size_t)192 * DEMB;       // 1024 x 256 x 64 fp16
    float* mpart = (float*)(Opart + (size_t)1024 * 256 * 64);
    float* lpart = mpart + (size_t)1024 * 256;

    convert_w<<<dim3(192 * DEMB / 256), dim3(256), 0, stream>>>(Wq, Wk, Wv, Wf);
    proj_mfma<<<dim3(B * T / 64), dim3(512), 0, stream>>>(
        x, Wf, bq, bk, bv, Qf, Kf, Vt);
    attn_partial<<<dim3(B * NPTILE * NSPLIT), dim3(512), 0, stream>>>(
        Qf, Kf, Vt, Opart, mpart, lpart);
    attn_combine<<<dim3(B * NPTILE * 16), dim3(256), 0, stream>>>(
        Opart, mpart, lpart, (float*)d_out);
}